// Round 11
// baseline (77747.241 us; speedup 1.0000x reference)
//
#include <hip/hip_runtime.h>

#define HID 512
#define NB  64
#define NT  1024
#define THX 0.1f
#define THH 0.05f
#define NTH 384          // 6 waves: tid -> (g = tid>>7, u = tid&127)

// ---- prep: gate-planar pack [1536][512] -> [3][512k][512u] ----
__global__ void pack_gp(const float* __restrict__ src, float* __restrict__ dst) {
    int idx = blockIdx.x * blockDim.x + threadIdx.x;
    if (idx < 3 * HID * HID) {
        int g = idx / (HID * HID), rem = idx % (HID * HID);
        int k = rem / HID, u = rem % HID;
        dst[idx] = src[(g * HID + u) * HID + k];
    }
}

// ---- prep: W_ih_l0 [1536][6] -> [3][6][512] ----
__global__ void pack_ih0g(const float* __restrict__ src, float* __restrict__ dst) {
    int idx = blockIdx.x * blockDim.x + threadIdx.x;
    if (idx < 3 * 6 * HID) {
        int g = idx / (6 * HID), rem = idx % (6 * HID);
        int f = rem / HID, u = rem % HID;
        dst[idx] = src[(g * HID + u) * 6 + f];
    }
}

// ---- init: zero list counts + padded barrier flags ----
__global__ void init_ws(int* __restrict__ cnts, int* __restrict__ bars) {
    int i = blockIdx.x * blockDim.x + threadIdx.x;
    if (i < 3 * 2 * NB * 4) cnts[i] = 0;
    if (i < NB * 64) bars[i] = 0;
}

__device__ __forceinline__ int cidx(int kind, int slot, int b, int q) {
    return ((kind * 2 + slot) * NB + b) * 4 + q;
}
__device__ __forceinline__ int lofs(int kind, int slot, int b, int q) {
    return (((kind * 2 + slot) * NB + b) * 4 + q) * 128;   // uint2 units
}

// ---- coherent relaxed ops (no fences -> L2 weight lines stay resident) ----
__device__ __forceinline__ int ld_cnt(const int* p) {
    return __hip_atomic_load(p, __ATOMIC_RELAXED, __HIP_MEMORY_SCOPE_AGENT);
}
__device__ __forceinline__ uint2 ld_ent(const uint2* p) {
    unsigned long long r = __hip_atomic_load((const unsigned long long*)p,
                             __ATOMIC_RELAXED, __HIP_MEMORY_SCOPE_AGENT);
    return make_uint2((unsigned)r, (unsigned)(r >> 32));
}
__device__ __forceinline__ void st_ent(uint2* p, unsigned a, unsigned bbits) {
    unsigned long long r = (unsigned long long)a | ((unsigned long long)bbits << 32);
    __hip_atomic_store((unsigned long long*)p, r, __ATOMIC_RELAXED, __HIP_MEMORY_SCOPE_AGENT);
}
__device__ __forceinline__ void st_cnt(int* p, int v) {
    __hip_atomic_store(p, v, __ATOMIC_RELAXED, __HIP_MEMORY_SCOPE_AGENT);
}

// ---- depth-16 pipelined sparse MAC, scalar row addressing ----
// wt = plane base + column (per thread); row k at wt[k<<9].
// n multiple of 16 (pads are (0,0) -> exact +0). Ascending consumption ->
// per-gate accumulation order identical to round 10.
__device__ __forceinline__ void mac_pipe16(const uint2* __restrict__ sl, int n,
                                           const float* __restrict__ wt, float& acc) {
    if (n <= 0) return;
    float v0,v1,v2,v3,v4,v5,v6,v7,v8,v9,v10,v11,v12,v13,v14,v15;
    float w0,w1,w2,w3,w4,w5,w6,w7,w8,w9,w10,w11,w12,w13,w14,w15;
#define PISS(S, IDX) { uint2 e_ = sl[(IDX)]; v##S = __uint_as_float(e_.y); \
    int kk_ = __builtin_amdgcn_readfirstlane((int)e_.x); \
    w##S = wt[(size_t)kk_ << 9]; }
#define PCON(S, NXT, MORE) { float t_ = v##S * w##S; if (MORE) PISS(S, (NXT)) \
    acc += t_; }
    PISS(0,0)  PISS(1,1)  PISS(2,2)  PISS(3,3)
    PISS(4,4)  PISS(5,5)  PISS(6,6)  PISS(7,7)
    PISS(8,8)  PISS(9,9)  PISS(10,10) PISS(11,11)
    PISS(12,12) PISS(13,13) PISS(14,14) PISS(15,15)
    #pragma unroll 1
    for (int i = 0; i < n; i += 16) {
        const int nx = i + 16;
        const bool more = nx < n;
        PCON(0,nx+0,more)  PCON(1,nx+1,more)  PCON(2,nx+2,more)  PCON(3,nx+3,more)
        PCON(4,nx+4,more)  PCON(5,nx+5,more)  PCON(6,nx+6,more)  PCON(7,nx+7,more)
        PCON(8,nx+8,more)  PCON(9,nx+9,more)  PCON(10,nx+10,more) PCON(11,nx+11,more)
        PCON(12,nx+12,more) PCON(13,nx+13,more) PCON(14,nx+14,more) PCON(15,nx+15,more)
    }
#undef PISS
#undef PCON
}

// ---- main kernel: 256 WGs = 64 batches x 4 unit-quarters (both layers) ----
// Each WG: units [q*128,(q+1)*128) of L0 (step t) AND L1 (step t-1).
// wgid%8 XCD mapping: each XCD holds one quarter-slice of all 3 matrices
// (2.25 MB) -> L2-resident (r9/r10: FETCH 100GB -> 1.2GB).
__global__ __launch_bounds__(NTH, 1)
void dgru_q(const float* __restrict__ x,
            const float* __restrict__ wih0g,   // [3][6][512]
            const float* __restrict__ whh0g,   // [3][512][512]
            const float* __restrict__ wih1g,
            const float* __restrict__ whh1g,
            const float* __restrict__ bih0, const float* __restrict__ bhh0,
            const float* __restrict__ bih1, const float* __restrict__ bhh1,
            const float* __restrict__ wfc,
            uint2* __restrict__ lists, int* __restrict__ cnts,
            int* __restrict__ bars, float* __restrict__ ws_fc) {
    __shared__ float s_x[2 * NT];               // 8 KB
    __shared__ float s_dx0[8];
    __shared__ float s_xp0[8];
    __shared__ uint2 s_lA[528], s_lB[528], s_lC[528];
    __shared__ float s_gp0[NTH]; __shared__ float s_gs0[128];
    __shared__ float s_gp1[NTH]; __shared__ float s_gs1[128];
    __shared__ int   s_c[3][2];
    __shared__ float s_fcw[2][2];

    const int wgid = blockIdx.x;
    const int bq   = wgid >> 2;
    const int q    = wgid & 3;
    const int tid  = threadIdx.x;
    const int lane = tid & 63;
    const int wv   = tid >> 6;        // 0..5
    const int g    = tid >> 7;        // 0..2 (wave-uniform: g = wv/2)
    const int u    = tid & 127;
    const int uu   = q * 128 + u;     // global unit id in [0,512)

    // gate-carry registers (per MAC thread (g,u))
    float accP0 = bih0[g * HID + uu] + ((g < 2) ? bhh0[g * HID + uu] : 0.f);
    float accS0 = (g == 2) ? bhh0[2 * HID + uu] : 0.f;
    float accP1 = bih1[g * HID + uu] + ((g < 2) ? bhh1[g * HID + uu] : 0.f);
    float accS1 = (g == 2) ? bhh1[2 * HID + uu] : 0.f;

    // unit-state registers (meaningful in tid<128)
    float h0 = 0.f, h0p = 0.f, xp1 = 0.f, h1 = 0.f, h1p = 0.f;
    float wfc0 = 0.f, wfc1 = 0.f;
    if (tid < 128) { wfc0 = wfc[q * 128 + tid]; wfc1 = wfc[HID + q * 128 + tid]; }

    // per-thread weight column pointers (plane base + column uu)
    const float* wA = whh0g + (size_t)g * HID * HID + uu;
    const float* wB = wih1g + (size_t)g * HID * HID + uu;
    const float* wC = whh1g + (size_t)g * HID * HID + uu;

    for (int i = tid; i < 2 * NT; i += NTH) s_x[i] = x[bq * 2 * NT + i];
    if (tid < 8) { s_xp0[tid] = 0.f; s_dx0[tid] = 0.f; }
    __syncthreads();

    for (int t = 0; t <= NT; ++t) {
        const int rs = t & 1, ps = (t + 1) & 1;
        // ===== stage phase: pull all needed lists into LDS ================
        int cA[4] = {0,0,0,0}, cB[4] = {0,0,0,0}, cC[4] = {0,0,0,0};
        int nA = 0, nB = 0, nC = 0;
        if (t < NT) {
            #pragma unroll
            for (int qq = 0; qq < 4; ++qq) { cA[qq] = ld_cnt(&cnts[cidx(0, rs, bq, qq)]); nA += cA[qq]; }
        }
        if (t > 0) {
            #pragma unroll
            for (int qq = 0; qq < 4; ++qq) {
                cB[qq] = ld_cnt(&cnts[cidx(1, rs, bq, qq)]); nB += cB[qq];
                cC[qq] = ld_cnt(&cnts[cidx(2, rs, bq, qq)]); nC += cC[qq];
            }
        }
        const int nApad = (nA + 15) & ~15;
        const int nBpad = (nB + 15) & ~15;
        const int nCpad = (nC + 15) & ~15;
        if (t < NT) {
            for (int i = tid; i < nApad; i += NTH) {
                if (i < nA) {
                    int xx = i, qq = 0;
                    while (xx >= cA[qq]) { xx -= cA[qq]; ++qq; }
                    s_lA[i] = ld_ent(lists + lofs(0, rs, bq, qq) + xx);
                } else s_lA[i] = make_uint2(0u, 0u);
            }
            if (tid < 6) {     // input features for step t
                float iv = s_x[2 * t], qv = s_x[2 * t + 1];
                float amp = sqrtf(iv * iv + qv * qv);
                float f;
                if      (tid == 0) f = iv;
                else if (tid == 1) f = qv;
                else if (tid == 2) f = amp;
                else if (tid == 3) f = amp * amp * amp;
                else if (tid == 4) f = qv / amp;
                else               f = iv / amp;
                float dx = f - s_xp0[tid];
                if (fabsf(dx) < THX) dx = 0.f; else s_xp0[tid] = f;
                s_dx0[tid] = dx;
            }
        }
        if (t > 0) {
            for (int i = tid; i < nBpad; i += NTH) {
                if (i < nB) {
                    int xx = i, qq = 0;
                    while (xx >= cB[qq]) { xx -= cB[qq]; ++qq; }
                    s_lB[i] = ld_ent(lists + lofs(1, rs, bq, qq) + xx);
                } else s_lB[i] = make_uint2(0u, 0u);
            }
            for (int i = tid; i < nCpad; i += NTH) {
                if (i < nC) {
                    int xx = i, qq = 0;
                    while (xx >= cC[qq]) { xx -= cC[qq]; ++qq; }
                    s_lC[i] = ld_ent(lists + lofs(2, rs, bq, qq) + xx);
                } else s_lC[i] = make_uint2(0u, 0u);
            }
        }
        __syncthreads();                                     // S1

        // ===== MAC phase (register accumulators, wave-uniform gate) =======
        if (t < NT) {
            #pragma unroll
            for (int f = 0; f < 6; ++f)                      // dv==0 adds exact +0
                accP0 += s_dx0[f] * wih0g[g * (6 * HID) + f * HID + uu];
            if (g < 2) mac_pipe16(s_lA, nApad, wA, accP0);   // hh -> r,z into accP
            else       mac_pipe16(s_lA, nApad, wA, accS0);   // hh -> nh into accS
            s_gp0[tid] = accP0;
            if (g == 2) s_gs0[u] = accS0;
        }
        if (t > 0) {
            mac_pipe16(s_lB, nBpad, wB, accP1);              // ih -> carry chain
            if (g < 2) mac_pipe16(s_lC, nCpad, wC, accP1);
            else       mac_pipe16(s_lC, nCpad, wC, accS1);
            s_gp1[tid] = accP1;
            if (g == 2) s_gs1[u] = accS1;
        }
        __syncthreads();                                     // S2

        // ===== unit phase: gates, h updates, deltas, FC partial ===========
        float dA = 0.f, dB = 0.f, dC = 0.f;
        bool nzA = false, nzB = false, nzC = false;
        unsigned long long mA = 0, mB = 0, mC = 0;
        if (tid < 128) {
            if (t < NT) {
                float ar = s_gp0[tid], az = s_gp0[128 + tid];
                float an = s_gp0[256 + tid], anh = s_gs0[tid];
                float r = 1.f / (1.f + expf(-ar));
                float z = 1.f / (1.f + expf(-az));
                float n = tanhf(an + r * anh);
                h0 = (1.f - z) * n + z * h0;
                dA = h0 - h0p; if (fabsf(dA) < THH) dA = 0.f; else h0p = h0;
                dB = h0 - xp1; if (fabsf(dB) < THX) dB = 0.f; else xp1 = h0;
                nzA = dA != 0.f; nzB = dB != 0.f;
            }
            if (t > 0) {
                float ar = s_gp1[tid], az = s_gp1[128 + tid];
                float an = s_gp1[256 + tid], anh = s_gs1[tid];
                float r = 1.f / (1.f + expf(-ar));
                float z = 1.f / (1.f + expf(-az));
                float n = tanhf(an + r * anh);
                h1 = (1.f - z) * n + z * h1;
                float p0 = h1 * wfc0, p1 = h1 * wfc1;
                #pragma unroll
                for (int off = 32; off > 0; off >>= 1) {
                    p0 += __shfl_down(p0, off, 64);
                    p1 += __shfl_down(p1, off, 64);
                }
                if (lane == 0) { s_fcw[wv][0] = p0; s_fcw[wv][1] = p1; }
            }
            if (t < NT) {
                dC = h1 - h1p; if (fabsf(dC) < THH) dC = 0.f; else h1p = h1;
                nzC = dC != 0.f;
            }
            mA = __ballot(nzA); mB = __ballot(nzB); mC = __ballot(nzC);
            if (lane == 0) {
                s_c[0][wv] = __popcll(mA);
                s_c[1][wv] = __popcll(mB);
                s_c[2][wv] = __popcll(mC);
            }
        }
        __syncthreads();                                     // S3

        // ===== publish phase ==============================================
        if (tid < 128) {
            unsigned long long below = (1ull << lane) - 1;
            if (t < NT) {
                int preA = (wv == 1) ? s_c[0][0] : 0;
                int preB = (wv == 1) ? s_c[1][0] : 0;
                int preC = (wv == 1) ? s_c[2][0] : 0;
                uint2* outA = lists + lofs(0, ps, bq, q);
                uint2* outB = lists + lofs(1, ps, bq, q);
                uint2* outC = lists + lofs(2, ps, bq, q);
                if (nzA) st_ent(&outA[preA + __popcll(mA & below)], (unsigned)uu, __float_as_uint(dA));
                if (nzB) st_ent(&outB[preB + __popcll(mB & below)], (unsigned)uu, __float_as_uint(dB));
                if (nzC) st_ent(&outC[preC + __popcll(mC & below)], (unsigned)uu, __float_as_uint(dC));
                if (tid == 0) {
                    st_cnt(&cnts[cidx(0, ps, bq, q)], s_c[0][0] + s_c[0][1]);
                    st_cnt(&cnts[cidx(1, ps, bq, q)], s_c[1][0] + s_c[1][1]);
                    st_cnt(&cnts[cidx(2, ps, bq, q)], s_c[2][0] + s_c[2][1]);
                }
            }
            if (t > 0 && tid == 0) {
                float2* dst = (float2*)(ws_fc + (((size_t)bq * NT + (t - 1)) * 4 + q) * 2);
                *dst = make_float2(s_fcw[0][0] + s_fcw[1][0], s_fcw[0][1] + s_fcw[1][1]);
            }
        }

        // ===== quad barrier (padded flag, release add, relaxed poll) ======
        if (t < NT) {
            __syncthreads();   // drains each wave's global stores (vmcnt) pre-arrival
            if (tid == 0) {
                __hip_atomic_fetch_add(&bars[bq * 64], 1, __ATOMIC_RELEASE,
                                       __HIP_MEMORY_SCOPE_AGENT);
                while (__hip_atomic_load(&bars[bq * 64], __ATOMIC_RELAXED,
                                         __HIP_MEMORY_SCOPE_AGENT) < 4 * (t + 1))
                    __builtin_amdgcn_s_sleep(8);
            }
            __syncthreads();
        }
    }
}

// ---- epilogue: deterministic FC reduction over 4 quarters ----
__global__ void fc_reduce(const float* __restrict__ ws_fc,
                          const float* __restrict__ bfc,
                          float* __restrict__ out) {
    int idx = blockIdx.x * blockDim.x + threadIdx.x;   // (b*NT + t)
    if (idx < NB * NT) {
        const float2* p = (const float2*)(ws_fc + (size_t)idx * 8);
        out[idx * 2 + 0] = bfc[0] + p[0].x + p[1].x + p[2].x + p[3].x;
        out[idx * 2 + 1] = bfc[1] + p[0].y + p[1].y + p[2].y + p[3].y;
    }
}

// ---- safety-net fallback (ws too small): dense branchy loops, inline FC ----
__global__ __launch_bounds__(512)
void dgru_raw(const float* __restrict__ x,
              const float* __restrict__ wih0, const float* __restrict__ whh0,
              const float* __restrict__ wih1, const float* __restrict__ whh1,
              const float* __restrict__ bih0, const float* __restrict__ bhh0,
              const float* __restrict__ bih1, const float* __restrict__ bhh1,
              const float* __restrict__ wfc,  const float* __restrict__ bfc,
              float* __restrict__ out) {
    __shared__ float s_dx0[8];
    __shared__ float s_xp0[8];
    __shared__ float s_dh0[HID];
    __shared__ float s_dx1[HID];
    __shared__ float s_dh1[HID];
    __shared__ float s_part[16];

    const int j = threadIdx.x;
    const int b = blockIdx.x;
    float h0 = 0.f, h0p = 0.f, xp1 = 0.f, h1 = 0.f, h1p = 0.f;
    float cr0 = bih0[j] + bhh0[j];
    float cz0 = bih0[HID + j] + bhh0[HID + j];
    float cn0 = bih0[2*HID + j];
    float cnh0 = bhh0[2*HID + j];
    float cr1 = bih1[j] + bhh1[j];
    float cz1 = bih1[HID + j] + bhh1[HID + j];
    float cn1 = bih1[2*HID + j];
    float cnh1 = bhh1[2*HID + j];
    if (j < 8) { s_xp0[j] = 0.f; s_dx0[j] = 0.f; }
    const float wfc0 = wfc[j], wfc1 = wfc[HID + j];
    __syncthreads();

    for (int t = 0; t < NT; ++t) {
        float d = h0 - h0p;
        if (fabsf(d) < THH) d = 0.f; else h0p = h0;
        s_dh0[j] = d;
        if (j < 6) {
            float iv = x[(b * NT + t) * 2 + 0];
            float qv = x[(b * NT + t) * 2 + 1];
            float amp = sqrtf(iv * iv + qv * qv);
            float f;
            if      (j == 0) f = iv;
            else if (j == 1) f = qv;
            else if (j == 2) f = amp;
            else if (j == 3) f = amp * amp * amp;
            else if (j == 4) f = qv / amp;
            else             f = iv / amp;
            float dx = f - s_xp0[j];
            if (fabsf(dx) < THX) dx = 0.f; else s_xp0[j] = f;
            s_dx0[j] = dx;
        }
        __syncthreads();
        {
            float ar = cr0, az = cz0, an = cn0, anh = cnh0;
            #pragma unroll
            for (int f = 0; f < 6; ++f) {
                float dv = s_dx0[f];
                ar += dv * wih0[j * 6 + f];
                az += dv * wih0[(HID + j) * 6 + f];
                an += dv * wih0[(2*HID + j) * 6 + f];
            }
            for (int k = 0; k < HID; ++k) {
                float dv = s_dh0[k];
                if (dv != 0.f) {
                    ar  += dv * whh0[j * HID + k];
                    az  += dv * whh0[(HID + j) * HID + k];
                    anh += dv * whh0[(2*HID + j) * HID + k];
                }
            }
            cr0 = ar; cz0 = az; cn0 = an; cnh0 = anh;
            float r = 1.f / (1.f + expf(-ar));
            float z = 1.f / (1.f + expf(-az));
            float n = tanhf(an + r * anh);
            h0 = (1.f - z) * n + z * h0;
        }
        float dxv = h0 - xp1;
        if (fabsf(dxv) < THX) dxv = 0.f; else xp1 = h0;
        s_dx1[j] = dxv;
        float dhv = h1 - h1p;
        if (fabsf(dhv) < THH) dhv = 0.f; else h1p = h1;
        s_dh1[j] = dhv;
        __syncthreads();
        {
            float ar = cr1, az = cz1, an = cn1, anh = cnh1;
            for (int k = 0; k < HID; ++k) {
                float dv = s_dx1[k];
                if (dv != 0.f) {
                    ar += dv * wih1[j * HID + k];
                    az += dv * wih1[(HID + j) * HID + k];
                    an += dv * wih1[(2*HID + j) * HID + k];
                }
            }
            for (int k = 0; k < HID; ++k) {
                float dv = s_dh1[k];
                if (dv != 0.f) {
                    ar  += dv * whh1[j * HID + k];
                    az  += dv * whh1[(HID + j) * HID + k];
                    anh += dv * whh1[(2*HID + j) * HID + k];
                }
            }
            cr1 = ar; cz1 = az; cn1 = an; cnh1 = anh;
            float r = 1.f / (1.f + expf(-ar));
            float z = 1.f / (1.f + expf(-az));
            float n = tanhf(an + r * anh);
            h1 = (1.f - z) * n + z * h1;
        }
        float p0 = h1 * wfc0, p1 = h1 * wfc1;
        #pragma unroll
        for (int off = 32; off > 0; off >>= 1) {
            p0 += __shfl_down(p0, off, 64);
            p1 += __shfl_down(p1, off, 64);
        }
        if ((j & 63) == 0) { s_part[(j >> 6) * 2] = p0; s_part[(j >> 6) * 2 + 1] = p1; }
        __syncthreads();
        if (j == 0) {
            float o0 = bfc[0], o1 = bfc[1];
            #pragma unroll
            for (int w = 0; w < 8; ++w) { o0 += s_part[w * 2]; o1 += s_part[w * 2 + 1]; }
            out[(b * NT + t) * 2 + 0] = o0;
            out[(b * NT + t) * 2 + 1] = o1;
        }
    }
}

extern "C" void kernel_launch(void* const* d_in, const int* in_sizes, int n_in,
                              void* d_out, int out_size, void* d_ws, size_t ws_size,
                              hipStream_t stream) {
    const float* x    = (const float*)d_in[0];
    // d_in[1] = h_0 : reference zero-inits h, input unused
    const float* wih0 = (const float*)d_in[2];
    const float* whh0 = (const float*)d_in[3];
    const float* bih0 = (const float*)d_in[4];
    const float* bhh0 = (const float*)d_in[5];
    const float* wih1 = (const float*)d_in[6];
    const float* whh1 = (const float*)d_in[7];
    const float* bih1 = (const float*)d_in[8];
    const float* bhh1 = (const float*)d_in[9];
    const float* wfc  = (const float*)d_in[10];
    const float* bfc  = (const float*)d_in[11];
    float* out = (float*)d_out;

    const size_t IH0G  = (size_t)3 * 6 * HID * sizeof(float);       // 36,864 B
    const size_t MATG  = (size_t)3 * HID * HID * sizeof(float);     // 3 MiB each
    const size_t o_ih0 = 0;
    const size_t o_hh0 = IH0G;
    const size_t o_ih1 = o_hh0 + MATG;
    const size_t o_hh1 = o_ih1 + MATG;
    const size_t o_lists = o_hh1 + MATG;
    const size_t LISTS_B = (size_t)3 * 2 * NB * 4 * 128 * 8;        // 1.5 MiB
    const size_t o_cnts  = o_lists + LISTS_B;
    const size_t o_bars  = o_cnts + (size_t)3 * 2 * NB * 4 * sizeof(int);
    const size_t o_fc    = o_bars + (size_t)NB * 64 * sizeof(int);
    const size_t FCB     = (size_t)NB * NT * 4 * 2 * sizeof(float); // 2 MiB
    const size_t need    = o_fc + FCB;                              // ~12.6 MiB

    if (ws_size >= need) {
        float* wt_ih0 = (float*)((char*)d_ws + o_ih0);
        float* wt_hh0 = (float*)((char*)d_ws + o_hh0);
        float* wt_ih1 = (float*)((char*)d_ws + o_ih1);
        float* wt_hh1 = (float*)((char*)d_ws + o_hh1);
        uint2* g_lists = (uint2*)((char*)d_ws + o_lists);
        int*   g_cnts  = (int*)((char*)d_ws + o_cnts);
        int*   g_bars  = (int*)((char*)d_ws + o_bars);
        float* g_fc    = (float*)((char*)d_ws + o_fc);

        pack_ih0g<<<(3 * 6 * HID + 255) / 256, 256, 0, stream>>>(wih0, wt_ih0);
        pack_gp<<<(3 * HID * HID + 255) / 256, 256, 0, stream>>>(whh0, wt_hh0);
        pack_gp<<<(3 * HID * HID + 255) / 256, 256, 0, stream>>>(wih1, wt_ih1);
        pack_gp<<<(3 * HID * HID + 255) / 256, 256, 0, stream>>>(whh1, wt_hh1);
        init_ws<<<4, 1024, 0, stream>>>(g_cnts, g_bars);
        dgru_q<<<4 * NB, NTH, 0, stream>>>(x, wt_ih0, wt_hh0, wt_ih1, wt_hh1,
                                           bih0, bhh0, bih1, bhh1, wfc,
                                           g_lists, g_cnts, g_bars, g_fc);
        fc_reduce<<<(NB * NT + 255) / 256, 256, 0, stream>>>(g_fc, bfc, out);
    } else {
        dgru_raw<<<NB, HID, 0, stream>>>(x, wih0, whh0, wih1, whh1,
                                         bih0, bhh0, bih1, bhh1, wfc, bfc, out);
    }
}

// Round 12
// 57704.083 us; speedup vs baseline: 1.3473x; 1.3473x over previous
//
#include <hip/hip_runtime.h>

#define HID 512
#define NB  64
#define NT  1024
#define THX 0.1f
#define THH 0.05f

// ---- prep: gate-planar pack [1536][512] -> [3][512k][512u] ----
__global__ void pack_gp(const float* __restrict__ src, float* __restrict__ dst) {
    int idx = blockIdx.x * blockDim.x + threadIdx.x;
    if (idx < 3 * HID * HID) {
        int g = idx / (HID * HID), rem = idx % (HID * HID);
        int k = rem / HID, u = rem % HID;
        dst[idx] = src[(g * HID + u) * HID + k];
    }
}

// ---- prep: W_ih_l0 [1536][6] -> [3][6][512] ----
__global__ void pack_ih0g(const float* __restrict__ src, float* __restrict__ dst) {
    int idx = blockIdx.x * blockDim.x + threadIdx.x;
    if (idx < 3 * 6 * HID) {
        int g = idx / (6 * HID), rem = idx % (6 * HID);
        int f = rem / HID, u = rem % HID;
        dst[idx] = src[(g * HID + u) * 6 + f];
    }
}

// ---- init: zero list counts + padded barrier flags ----
__global__ void init_ws(int* __restrict__ cnts, int* __restrict__ bars) {
    int i = blockIdx.x * blockDim.x + threadIdx.x;
    if (i < 3 * 2 * NB * 2) cnts[i] = 0;
    if (i < NB * 64) bars[i] = 0;
}

__device__ __forceinline__ int cidx(int kind, int slot, int b, int half) {
    return ((kind * 2 + slot) * NB + b) * 2 + half;
}
__device__ __forceinline__ int lofs(int kind, int slot, int b, int half) {
    return (((kind * 2 + slot) * NB + b) * 2 + half) * 256;   // uint2 units
}

// ---- coherent relaxed loads (no fences -> L2 weight lines stay resident) ----
__device__ __forceinline__ int ld_cnt(const int* p) {
    return __hip_atomic_load(p, __ATOMIC_RELAXED, __HIP_MEMORY_SCOPE_AGENT);
}
__device__ __forceinline__ uint2 ld_ent(const uint2* p) {
    unsigned long long r = __hip_atomic_load((const unsigned long long*)p,
                             __ATOMIC_RELAXED, __HIP_MEMORY_SCOPE_AGENT);
    return make_uint2((unsigned)r, (unsigned)(r >> 32));
}

// ---- depth-8 pipelined sparse MAC, scalar row addressing ----
// wt = gate-plane base (wave-uniform); row k at wt + (k<<9); per-lane column uu.
// Per entry: ds_read_b64 + readfirstlane + saddr load + fma (~4 VALU issues,
// vs r10's ~9-10 with per-lane 64-bit addressing + cndmask accumulator select).
// n multiple of 8; pads (0,0) add exact +0. Ascending order preserved.
__device__ __forceinline__ void mac_pipe8(const uint2* __restrict__ sl, int n,
                                          const float* __restrict__ wt, int uu,
                                          float& acc) {
    if (n <= 0) return;
    float v0, v1, v2, v3, v4, v5, v6, v7;
    float w0, w1, w2, w3, w4, w5, w6, w7;
#define PISS(S, IDX) { uint2 e_ = sl[(IDX)]; v##S = __uint_as_float(e_.y); \
    int kk_ = __builtin_amdgcn_readfirstlane((int)e_.x); \
    const float* row_ = wt + ((size_t)kk_ << 9); \
    w##S = row_[uu]; }
#define PCON(S, NXT, MORE) { float t_ = v##S * w##S; if (MORE) PISS(S, (NXT)) \
    acc += t_; }
    PISS(0,0) PISS(1,1) PISS(2,2) PISS(3,3)
    PISS(4,4) PISS(5,5) PISS(6,6) PISS(7,7)
    #pragma unroll 1
    for (int i = 0; i < n; i += 8) {
        const int nx = i + 8;
        const bool more = nx < n;
        PCON(0,nx+0,more) PCON(1,nx+1,more) PCON(2,nx+2,more) PCON(3,nx+3,more)
        PCON(4,nx+4,more) PCON(5,nx+5,more) PCON(6,nx+6,more) PCON(7,nx+7,more)
    }
#undef PISS
#undef PCON
}

// ---- main kernel: 256 WGs = 64 batches x {L0,L1} x {half lo,hi} ----
// 1024 threads: role = tid>>8 (WAVE-UNIFORM gate: 0=r,1=z,2=n,3=nh), u = tid&255.
// Gate-planar weights; fresh per-list partial sums block-added to carries
// (matches reference mac_x + mac_h structure). r10's fence-free quad sync.
__global__ __launch_bounds__(1024, 4)
void dgru_split(const float* __restrict__ x,
                const float* __restrict__ wih0g,   // [3][6][512]
                const float* __restrict__ whh0g,   // [3][512][512]
                const float* __restrict__ wih1g,
                const float* __restrict__ whh1g,
                const float* __restrict__ bih0, const float* __restrict__ bhh0,
                const float* __restrict__ bih1, const float* __restrict__ bhh1,
                const float* __restrict__ wfc,
                uint2* __restrict__ lists, int* __restrict__ cnts,
                int* __restrict__ bars, float* __restrict__ ws_fc) {
    __shared__ float s_x[2 * NT];                  // 8 KB (L0 only)
    __shared__ float s_dx0[8];
    __shared__ float s_xp0[8];
    __shared__ uint2 s_lA[520];                    // L0: dh0 merged
    __shared__ uint2 s_lB[520];                    // L1: dx1 merged
    __shared__ uint2 s_lC[520];                    // L1: dh1 merged
    __shared__ float s_gate[1024];
    __shared__ int   s_c1[4], s_c2[4];
    __shared__ float s_fcp[4][2];

    const int wgid  = blockIdx.x;
    const int bq    = wgid >> 2;
    const int layer = (wgid >> 1) & 1;
    const int half  = wgid & 1;
    const int tid   = threadIdx.x;
    const int lane  = tid & 63;
    const int wv    = tid >> 6;                    // 0..15
    const int role  = tid >> 8;                    // 0..3, wave-uniform
    const int u     = tid & 255;
    const int uu    = half * 256 + u;
    const int srole = __builtin_amdgcn_readfirstlane(role);
    const int pl    = __builtin_amdgcn_readfirstlane(role < 2 ? role : 2);

    const float* bih = layer ? bih1 : bih0;
    const float* bhh = layer ? bhh1 : bhh0;

    // per-(role,u) gate carry:  r,z: bih+bhh | n: bih | nh: bhh
    float carry;
    if (srole == 0)      carry = bih[uu]        + bhh[uu];
    else if (srole == 1) carry = bih[HID + uu]  + bhh[HID + uu];
    else if (srole == 2) carry = bih[2*HID + uu];
    else                 carry = bhh[2*HID + uu];

    // unit state (threads 0..255)
    float h = 0.f, hp = 0.f, xp1 = 0.f;
    float wfc0 = 0.f, wfc1 = 0.f;
    if (tid < 256) { wfc0 = wfc[uu]; wfc1 = wfc[HID + uu]; }

    // wave-uniform gate-plane bases
    const float* wIH0 = wih0g + pl * (6 * HID);
    const float* wHH  = (layer ? whh1g : whh0g) + (size_t)pl * (HID * HID);
    const float* wIH1 = wih1g + (size_t)pl * (HID * HID);

    if (layer == 0)
        for (int i = tid; i < 2 * NT; i += 1024) s_x[i] = x[bq * 2 * NT + i];
    if (tid < 8) { s_xp0[tid] = 0.f; s_dx0[tid] = 0.f; }
    __syncthreads();

    for (int t = 0; t <= NT; ++t) {
        const int rs = t & 1, ps = (t + 1) & 1;
        if (layer == 0) {
            if (t < NT) {
                // ---- stage merged listA(rs): lo then hi (k ascending) ----
                int cLo = ld_cnt(&cnts[cidx(0, rs, bq, 0)]);
                int cHi = ld_cnt(&cnts[cidx(0, rs, bq, 1)]);
                int ntot = cLo + cHi, n1 = (ntot + 7) & ~7;
                const uint2* gLo = lists + lofs(0, rs, bq, 0);
                const uint2* gHi = lists + lofs(0, rs, bq, 1);
                if (tid < cLo)       s_lA[tid] = ld_ent(&gLo[tid]);
                else if (tid < ntot) s_lA[tid] = ld_ent(&gHi[tid - cLo]);
                else if (tid < n1)   s_lA[tid] = make_uint2(0u, 0u);
                if (tid < 6) {                       // input features, step t
                    float iv = s_x[2 * t], qv = s_x[2 * t + 1];
                    float amp = sqrtf(iv * iv + qv * qv);
                    float f;
                    if      (tid == 0) f = iv;
                    else if (tid == 1) f = qv;
                    else if (tid == 2) f = amp;
                    else if (tid == 3) f = amp * amp * amp;
                    else if (tid == 4) f = qv / amp;
                    else               f = iv / amp;
                    float dx = f - s_xp0[tid];
                    if (fabsf(dx) < THX) dx = 0.f; else s_xp0[tid] = f;
                    s_dx0[tid] = dx;
                }
                __syncthreads();                                     // S1
                // ---- MAC: fresh block sums, wave-uniform dest register ----
                float ihacc = 0.f, hhacc = 0.f;
                if (srole != 3) {                    // r,z,n get ih terms
                    #pragma unroll
                    for (int f = 0; f < 6; ++f)      // dv==0 adds exact +0
                        ihacc += s_dx0[f] * wIH0[f * HID + uu];
                }
                if (srole != 2)                      // r,z,nh get hh terms
                    mac_pipe8(s_lA, n1, wHH, uu, hhacc);
                if (srole != 3) carry += ihacc;      // (dm + sum_ih)
                if (srole != 2) carry += hhacc;      // ... + sum_hh (ref block order)
                s_gate[tid] = carry;
                __syncthreads();                                     // S2
                // ---- unit phase ----
                float dA = 0.f, dB = 0.f;
                bool nzA = false, nzB = false;
                unsigned long long mA = 0, mB = 0;
                if (tid < 256) {
                    float ar = s_gate[tid],       az  = s_gate[256 + tid];
                    float an = s_gate[512 + tid], anh = s_gate[768 + tid];
                    float r = 1.f / (1.f + expf(-ar));
                    float z = 1.f / (1.f + expf(-az));
                    float n = tanhf(an + r * anh);
                    h = (1.f - z) * n + z * h;
                    dA = h - hp;  if (fabsf(dA) < THH) dA = 0.f; else hp = h;
                    dB = h - xp1; if (fabsf(dB) < THX) dB = 0.f; else xp1 = h;
                    nzA = dA != 0.f; nzB = dB != 0.f;
                    mA = __ballot(nzA); mB = __ballot(nzB);
                    if (lane == 0) { s_c1[wv] = __popcll(mA); s_c2[wv] = __popcll(mB); }
                }
                __syncthreads();                                     // S3
                if (tid < 256) {
                    int baseA = 0, baseB = 0, totA = 0, totB = 0;
                    #pragma unroll
                    for (int w = 0; w < 4; ++w) {
                        baseA += (w < wv) ? s_c1[w] : 0;  totA += s_c1[w];
                        baseB += (w < wv) ? s_c2[w] : 0;  totB += s_c2[w];
                    }
                    uint2* outA = lists + lofs(0, ps, bq, half);
                    uint2* outB = lists + lofs(1, ps, bq, half);
                    unsigned long long below = (1ull << lane) - 1;
                    if (nzA) outA[baseA + __popcll(mA & below)] =
                        make_uint2((unsigned)uu, __float_as_uint(dA));
                    if (nzB) outB[baseB + __popcll(mB & below)] =
                        make_uint2((unsigned)uu, __float_as_uint(dB));
                    if (tid == 0) {
                        cnts[cidx(0, ps, bq, half)] = totA;
                        cnts[cidx(1, ps, bq, half)] = totB;
                    }
                }
            }
        } else {
            if (t > 0) {
                // ---- L1 step t-1: stage merged listB(rs), listC(rs) ----
                int cBlo = ld_cnt(&cnts[cidx(1, rs, bq, 0)]);
                int cBhi = ld_cnt(&cnts[cidx(1, rs, bq, 1)]);
                int cClo = ld_cnt(&cnts[cidx(2, rs, bq, 0)]);
                int cChi = ld_cnt(&cnts[cidx(2, rs, bq, 1)]);
                int ntB = cBlo + cBhi, nB = (ntB + 7) & ~7;
                int ntC = cClo + cChi, nC = (ntC + 7) & ~7;
                const uint2* gBlo = lists + lofs(1, rs, bq, 0);
                const uint2* gBhi = lists + lofs(1, rs, bq, 1);
                const uint2* gClo = lists + lofs(2, rs, bq, 0);
                const uint2* gChi = lists + lofs(2, rs, bq, 1);
                if (tid < cBlo)      s_lB[tid] = ld_ent(&gBlo[tid]);
                else if (tid < ntB)  s_lB[tid] = ld_ent(&gBhi[tid - cBlo]);
                else if (tid < nB)   s_lB[tid] = make_uint2(0u, 0u);
                if (tid < cClo)      s_lC[tid] = ld_ent(&gClo[tid]);
                else if (tid < ntC)  s_lC[tid] = ld_ent(&gChi[tid - cClo]);
                else if (tid < nC)   s_lC[tid] = make_uint2(0u, 0u);
                __syncthreads();                                     // S1
                // ---- MAC ----
                float bacc = 0.f, cacc = 0.f;
                if (srole != 3) mac_pipe8(s_lB, nB, wIH1, uu, bacc);
                if (srole != 2) mac_pipe8(s_lC, nC, wHH,  uu, cacc);
                if (srole != 3) carry += bacc;       // (dm + sum_ih)
                if (srole != 2) carry += cacc;       // ... + sum_hh
                s_gate[tid] = carry;
                __syncthreads();                                     // S2
                // ---- unit phase ----
                float dC = 0.f; bool nzC = false; unsigned long long mC = 0;
                if (tid < 256) {
                    float ar = s_gate[tid],       az  = s_gate[256 + tid];
                    float an = s_gate[512 + tid], anh = s_gate[768 + tid];
                    float r = 1.f / (1.f + expf(-ar));
                    float z = 1.f / (1.f + expf(-az));
                    float n = tanhf(an + r * anh);
                    h = (1.f - z) * n + z * h;
                    float p0 = h * wfc0, p1 = h * wfc1;
                    #pragma unroll
                    for (int off = 32; off > 0; off >>= 1) {
                        p0 += __shfl_down(p0, off, 64);
                        p1 += __shfl_down(p1, off, 64);
                    }
                    if (lane == 0) { s_fcp[wv][0] = p0; s_fcp[wv][1] = p1; }
                    dC = h - hp; if (fabsf(dC) < THH) dC = 0.f; else hp = h;
                    nzC = dC != 0.f;
                    mC = __ballot(nzC);
                    if (lane == 0) s_c1[wv] = __popcll(mC);
                }
                __syncthreads();                                     // S3
                if (tid < 256) {
                    int baseC = 0, totC = 0;
                    #pragma unroll
                    for (int w = 0; w < 4; ++w) {
                        baseC += (w < wv) ? s_c1[w] : 0;  totC += s_c1[w];
                    }
                    uint2* outC = lists + lofs(2, ps, bq, half);
                    unsigned long long below = (1ull << lane) - 1;
                    if (nzC) outC[baseC + __popcll(mC & below)] =
                        make_uint2((unsigned)uu, __float_as_uint(dC));
                    if (tid == 0) {
                        cnts[cidx(2, ps, bq, half)] = totC;
                        float2* dst = (float2*)(ws_fc +
                            (((size_t)bq * NT + (t - 1)) * 2 + half) * 2);
                        *dst = make_float2(s_fcp[0][0] + s_fcp[1][0] + s_fcp[2][0] + s_fcp[3][0],
                                           s_fcp[0][1] + s_fcp[1][1] + s_fcp[2][1] + s_fcp[3][1]);
                    }
                }
            }
        }
        // ---- quad barrier (padded flag, release add, relaxed poll) ----
        if (t < NT) {
            __syncthreads();   // drains this WG's global stores before arrival
            if (tid == 0) {
                __hip_atomic_fetch_add(&bars[bq * 64], 1, __ATOMIC_RELEASE,
                                       __HIP_MEMORY_SCOPE_AGENT);
                while (__hip_atomic_load(&bars[bq * 64], __ATOMIC_RELAXED,
                                         __HIP_MEMORY_SCOPE_AGENT) < 4 * (t + 1))
                    __builtin_amdgcn_s_sleep(8);
            }
            __syncthreads();
        }
    }
}

// ---- epilogue: deterministic FC reduction (lo half + hi half + bias) ----
__global__ void fc_reduce(const float* __restrict__ ws_fc,
                          const float* __restrict__ bfc,
                          float* __restrict__ out) {
    int idx = blockIdx.x * blockDim.x + threadIdx.x;   // (b*NT + t)
    if (idx < NB * NT) {
        const float2* p = (const float2*)(ws_fc + (size_t)idx * 4);
        out[idx * 2 + 0] = bfc[0] + p[0].x + p[1].x;
        out[idx * 2 + 1] = bfc[1] + p[0].y + p[1].y;
    }
}

// ---- safety-net fallback (ws too small): dense branchy loops, inline FC ----
__global__ __launch_bounds__(512)
void dgru_raw(const float* __restrict__ x,
              const float* __restrict__ wih0, const float* __restrict__ whh0,
              const float* __restrict__ wih1, const float* __restrict__ whh1,
              const float* __restrict__ bih0, const float* __restrict__ bhh0,
              const float* __restrict__ bih1, const float* __restrict__ bhh1,
              const float* __restrict__ wfc,  const float* __restrict__ bfc,
              float* __restrict__ out) {
    __shared__ float s_dx0[8];
    __shared__ float s_xp0[8];
    __shared__ float s_dh0[HID];
    __shared__ float s_dx1[HID];
    __shared__ float s_dh1[HID];
    __shared__ float s_part[16];

    const int j = threadIdx.x;
    const int b = blockIdx.x;
    float h0 = 0.f, h0p = 0.f, xp1 = 0.f, h1 = 0.f, h1p = 0.f;
    float cr0 = bih0[j] + bhh0[j];
    float cz0 = bih0[HID + j] + bhh0[HID + j];
    float cn0 = bih0[2*HID + j];
    float cnh0 = bhh0[2*HID + j];
    float cr1 = bih1[j] + bhh1[j];
    float cz1 = bih1[HID + j] + bhh1[HID + j];
    float cn1 = bih1[2*HID + j];
    float cnh1 = bhh1[2*HID + j];
    if (j < 8) { s_xp0[j] = 0.f; s_dx0[j] = 0.f; }
    const float wfc0 = wfc[j], wfc1 = wfc[HID + j];
    __syncthreads();

    for (int t = 0; t < NT; ++t) {
        float d = h0 - h0p;
        if (fabsf(d) < THH) d = 0.f; else h0p = h0;
        s_dh0[j] = d;
        if (j < 6) {
            float iv = x[(b * NT + t) * 2 + 0];
            float qv = x[(b * NT + t) * 2 + 1];
            float amp = sqrtf(iv * iv + qv * qv);
            float f;
            if      (j == 0) f = iv;
            else if (j == 1) f = qv;
            else if (j == 2) f = amp;
            else if (j == 3) f = amp * amp * amp;
            else if (j == 4) f = qv / amp;
            else             f = iv / amp;
            float dx = f - s_xp0[j];
            if (fabsf(dx) < THX) dx = 0.f; else s_xp0[j] = f;
            s_dx0[j] = dx;
        }
        __syncthreads();
        {
            float ar = cr0, az = cz0, an = cn0, anh = cnh0;
            #pragma unroll
            for (int f = 0; f < 6; ++f) {
                float dv = s_dx0[f];
                ar += dv * wih0[j * 6 + f];
                az += dv * wih0[(HID + j) * 6 + f];
                an += dv * wih0[(2*HID + j) * 6 + f];
            }
            for (int k = 0; k < HID; ++k) {
                float dv = s_dh0[k];
                if (dv != 0.f) {
                    ar  += dv * whh0[j * HID + k];
                    az  += dv * whh0[(HID + j) * HID + k];
                    anh += dv * whh0[(2*HID + j) * HID + k];
                }
            }
            cr0 = ar; cz0 = az; cn0 = an; cnh0 = anh;
            float r = 1.f / (1.f + expf(-ar));
            float z = 1.f / (1.f + expf(-az));
            float n = tanhf(an + r * anh);
            h0 = (1.f - z) * n + z * h0;
        }
        float dxv = h0 - xp1;
        if (fabsf(dxv) < THX) dxv = 0.f; else xp1 = h0;
        s_dx1[j] = dxv;
        float dhv = h1 - h1p;
        if (fabsf(dhv) < THH) dhv = 0.f; else h1p = h1;
        s_dh1[j] = dhv;
        __syncthreads();
        {
            float ar = cr1, az = cz1, an = cn1, anh = cnh1;
            for (int k = 0; k < HID; ++k) {
                float dv = s_dx1[k];
                if (dv != 0.f) {
                    ar += dv * wih1[j * HID + k];
                    az += dv * wih1[(HID + j) * HID + k];
                    an += dv * wih1[(2*HID + j) * HID + k];
                }
            }
            for (int k = 0; k < HID; ++k) {
                float dv = s_dh1[k];
                if (dv != 0.f) {
                    ar  += dv * whh1[j * HID + k];
                    az  += dv * whh1[(HID + j) * HID + k];
                    anh += dv * whh1[(2*HID + j) * HID + k];
                }
            }
            cr1 = ar; cz1 = az; cn1 = an; cnh1 = anh;
            float r = 1.f / (1.f + expf(-ar));
            float z = 1.f / (1.f + expf(-az));
            float n = tanhf(an + r * anh);
            h1 = (1.f - z) * n + z * h1;
        }
        float p0 = h1 * wfc0, p1 = h1 * wfc1;
        #pragma unroll
        for (int off = 32; off > 0; off >>= 1) {
            p0 += __shfl_down(p0, off, 64);
            p1 += __shfl_down(p1, off, 64);
        }
        if ((j & 63) == 0) { s_part[(j >> 6) * 2] = p0; s_part[(j >> 6) * 2 + 1] = p1; }
        __syncthreads();
        if (j == 0) {
            float o0 = bfc[0], o1 = bfc[1];
            #pragma unroll
            for (int w = 0; w < 8; ++w) { o0 += s_part[w * 2]; o1 += s_part[w * 2 + 1]; }
            out[(b * NT + t) * 2 + 0] = o0;
            out[(b * NT + t) * 2 + 1] = o1;
        }
    }
}

extern "C" void kernel_launch(void* const* d_in, const int* in_sizes, int n_in,
                              void* d_out, int out_size, void* d_ws, size_t ws_size,
                              hipStream_t stream) {
    const float* x    = (const float*)d_in[0];
    // d_in[1] = h_0 : reference zero-inits h, input unused
    const float* wih0 = (const float*)d_in[2];
    const float* whh0 = (const float*)d_in[3];
    const float* bih0 = (const float*)d_in[4];
    const float* bhh0 = (const float*)d_in[5];
    const float* wih1 = (const float*)d_in[6];
    const float* whh1 = (const float*)d_in[7];
    const float* bih1 = (const float*)d_in[8];
    const float* bhh1 = (const float*)d_in[9];
    const float* wfc  = (const float*)d_in[10];
    const float* bfc  = (const float*)d_in[11];
    float* out = (float*)d_out;

    const size_t IH0G  = (size_t)3 * 6 * HID * sizeof(float);       // 36,864 B
    const size_t MATG  = (size_t)3 * HID * HID * sizeof(float);     // 3 MiB each
    const size_t o_ih0 = 0;
    const size_t o_hh0 = IH0G;
    const size_t o_ih1 = o_hh0 + MATG;
    const size_t o_hh1 = o_ih1 + MATG;
    const size_t o_lists = o_hh1 + MATG;
    const size_t LISTS_B = (size_t)3 * 2 * NB * 2 * 256 * 8;        // 1.5 MiB
    const size_t o_cnts  = o_lists + LISTS_B;
    const size_t o_bars  = o_cnts + (size_t)3 * 2 * NB * 2 * sizeof(int);
    const size_t o_fc    = o_bars + (size_t)NB * 64 * sizeof(int);
    const size_t FCB     = (size_t)NB * NT * 4 * sizeof(float);     // 1 MiB
    const size_t need    = o_fc + FCB;                              // ~12 MiB

    if (ws_size >= need) {
        float* wt_ih0 = (float*)((char*)d_ws + o_ih0);
        float* wt_hh0 = (float*)((char*)d_ws + o_hh0);
        float* wt_ih1 = (float*)((char*)d_ws + o_ih1);
        float* wt_hh1 = (float*)((char*)d_ws + o_hh1);
        uint2* g_lists = (uint2*)((char*)d_ws + o_lists);
        int*   g_cnts  = (int*)((char*)d_ws + o_cnts);
        int*   g_bars  = (int*)((char*)d_ws + o_bars);
        float* g_fc    = (float*)((char*)d_ws + o_fc);

        pack_ih0g<<<(3 * 6 * HID + 255) / 256, 256, 0, stream>>>(wih0, wt_ih0);
        pack_gp<<<(3 * HID * HID + 255) / 256, 256, 0, stream>>>(whh0, wt_hh0);
        pack_gp<<<(3 * HID * HID + 255) / 256, 256, 0, stream>>>(wih1, wt_ih1);
        pack_gp<<<(3 * HID * HID + 255) / 256, 256, 0, stream>>>(whh1, wt_hh1);
        init_ws<<<4, 1024, 0, stream>>>(g_cnts, g_bars);
        dgru_split<<<4 * NB, 1024, 0, stream>>>(x, wt_ih0, wt_hh0, wt_ih1, wt_hh1,
                                                bih0, bhh0, bih1, bhh1, wfc,
                                                g_lists, g_cnts, g_bars, g_fc);
        fc_reduce<<<(NB * NT + 255) / 256, 256, 0, stream>>>(g_fc, bfc, out);
    } else {
        dgru_raw<<<NB, HID, 0, stream>>>(x, wih0, whh0, wih1, whh1,
                                         bih0, bhh0, bih1, bhh1, wfc, bfc, out);
    }
}

// Round 13
// 54219.708 us; speedup vs baseline: 1.4339x; 1.0643x over previous
//
#include <hip/hip_runtime.h>

#define HID 512
#define NB  64
#define NT  1024
#define THX 0.1f
#define THH 0.05f

// ---- prep: pack W_ih_l0 [1536][6] f32 -> [6][512]{r,z,n} float3 ----
__global__ void pack_ih0(const float* __restrict__ src, float* __restrict__ dst) {
    int idx = blockIdx.x * blockDim.x + threadIdx.x;
    if (idx < 6 * HID) {
        int f = idx / HID, j = idx % HID;
        dst[f * 1536 + j * 3 + 0] = src[(0 * HID + j) * 6 + f];
        dst[f * 1536 + j * 3 + 1] = src[(1 * HID + j) * 6 + f];
        dst[f * 1536 + j * 3 + 2] = src[(2 * HID + j) * 6 + f];
    }
}

// ---- prep: pack a [1536][512] f32 matrix -> [512(k)][512(j)]{r,z,n} float3 ----
__global__ void pack_h3(const float* __restrict__ src, float* __restrict__ dst) {
    int idx = blockIdx.x * blockDim.x + threadIdx.x;
    if (idx < HID * HID) {
        int k = idx / HID, j = idx % HID;
        dst[k * 1536 + j * 3 + 0] = src[(0 * HID + j) * HID + k];
        dst[k * 1536 + j * 3 + 1] = src[(1 * HID + j) * HID + k];
        dst[k * 1536 + j * 3 + 2] = src[(2 * HID + j) * HID + k];
    }
}

// ---- init: zero list counts + padded barrier flags ----
__global__ void init_ws(int* __restrict__ cnts, int* __restrict__ bars) {
    int i = blockIdx.x * blockDim.x + threadIdx.x;
    if (i < 3 * 2 * NB * 2) cnts[i] = 0;
    if (i < NB * 64) bars[i] = 0;
}

__device__ __forceinline__ int cidx(int kind, int slot, int b, int half) {
    return ((kind * 2 + slot) * NB + b) * 2 + half;
}
__device__ __forceinline__ int lofs(int kind, int slot, int b, int half) {
    return (((kind * 2 + slot) * NB + b) * 2 + half) * 256;   // uint2 units
}

// ---- coherent relaxed loads (no fences -> L2 weight lines stay resident) ----
__device__ __forceinline__ int ld_cnt(const int* p) {
    return __hip_atomic_load(p, __ATOMIC_RELAXED, __HIP_MEMORY_SCOPE_AGENT);
}
__device__ __forceinline__ uint2 ld_ent(const uint2* p) {
    unsigned long long r = __hip_atomic_load((const unsigned long long*)p,
                             __ATOMIC_RELAXED, __HIP_MEMORY_SCOPE_AGENT);
    return make_uint2((unsigned)r, (unsigned)(r >> 32));
}

// ---- depth-8 pipelined sparse MAC (r10's proven vehicle, de-fattened) ----
// List entries carry PRE-MULTIPLIED byte row offsets (e.x = k*6144), so the
// per-entry body is: ds_read_b64 + 64-bit add + global_load_dword + fma —
// no shifts, no accumulator select (vs r10's ~10 VALU issues/entry).
// n multiple of 8; pads (0,0) -> row 0 with v=0 -> exact +0 adds; ascending.
__device__ __forceinline__ void mac_pipe8(const uint2* __restrict__ sl, int n,
                                          const float* __restrict__ wt,
                                          float& acc) {
    if (n <= 0) return;
    float v0, v1, v2, v3, v4, v5, v6, v7;
    float w0, w1, w2, w3, w4, w5, w6, w7;
#define PISS(S, IDX) { uint2 e_ = sl[(IDX)]; v##S = __uint_as_float(e_.y); \
    w##S = *(const float*)((const char*)wt + e_.x); }
#define PCON(S, NXT, MORE) { float t_ = v##S * w##S; if (MORE) PISS(S, (NXT)) \
    acc += t_; }
    PISS(0,0) PISS(1,1) PISS(2,2) PISS(3,3)
    PISS(4,4) PISS(5,5) PISS(6,6) PISS(7,7)
    #pragma unroll 1
    for (int i = 0; i < n; i += 8) {
        const int nx = i + 8;
        const bool more = nx < n;
        PCON(0,nx+0,more) PCON(1,nx+1,more) PCON(2,nx+2,more) PCON(3,nx+3,more)
        PCON(4,nx+4,more) PCON(5,nx+5,more) PCON(6,nx+6,more) PCON(7,nx+7,more)
    }
#undef PISS
#undef PCON
}

// ---- main kernel: 256 WGs = 64 batches x {L0,L1} x {half lo,hi} ----
// 1024 threads: u = tid>>2, role = tid&3 (0->r, 1->z, 2->n[ih], 3->nh[hh]).
// Unconditional MACs into fresh aI/aH; merged once per step into the carry
// (block order validated in r12: absmax 0.0137). r10's fence-free quad sync.
__global__ __launch_bounds__(1024, 4)
void dgru_split(const float* __restrict__ x,
                const float* __restrict__ wih0p,   // [6][512] float3
                const float* __restrict__ whh0p,   // [512][512] float3
                const float* __restrict__ wih1p,
                const float* __restrict__ whh1p,
                const float* __restrict__ bih0, const float* __restrict__ bhh0,
                const float* __restrict__ bih1, const float* __restrict__ bhh1,
                const float* __restrict__ wfc,
                uint2* __restrict__ lists, int* __restrict__ cnts,
                int* __restrict__ bars, float* __restrict__ ws_fc) {
    __shared__ float s_x[2 * NT];                  // 8 KB (L0 only)
    __shared__ float s_dx0[8];
    __shared__ float s_xp0[8];
    __shared__ uint2 s_l1[520];
    __shared__ uint2 s_l2[520];
    __shared__ int   s_c1[16], s_c2[16];
    __shared__ float s_fcp[16][2];

    const int wgid  = blockIdx.x;
    const int bq    = wgid >> 2;
    const int layer = (wgid >> 1) & 1;
    const int half  = wgid & 1;
    const int tid   = threadIdx.x;
    const int lane  = tid & 63;
    const int wave  = tid >> 6;
    const int u     = tid >> 2;
    const int role  = tid & 3;
    const int colr  = (role < 2) ? role : 2;    // role3 aliases the n column
    const int uu    = half * 256 + u;

    const float* bih = layer ? bih1 : bih0;
    const float* bhh = layer ? bhh1 : bhh0;

    // per-(role,u) gate carry:  r,z: bih+bhh | n: bih | nh: bhh
    float carry;
    if (role == 0)      carry = bih[uu]        + bhh[uu];
    else if (role == 1) carry = bih[HID + uu]  + bhh[HID + uu];
    else if (role == 2) carry = bih[2*HID + uu];
    else                carry = bhh[2*HID + uu];

    float h = 0.f, hp = 0.f, xp1 = 0.f;
    float wfc0 = 0.f, wfc1 = 0.f;
    { wfc0 = wfc[uu]; wfc1 = wfc[HID + uu]; }

    // per-lane column pointers (row 0 of each matrix, this thread's column)
    const float* wih0c = wih0p + uu * 3 + colr;    // [6][512]f3, stride 1536 floats
    const float* whh0c = whh0p + uu * 3 + colr;    // row k at byte offset k*6144
    const float* wih1c = wih1p + uu * 3 + colr;
    const float* whh1c = whh1p + uu * 3 + colr;

    if (layer == 0)
        for (int i = tid; i < 2 * NT; i += 1024) s_x[i] = x[bq * 2 * NT + i];
    if (tid < 8) { s_xp0[tid] = 0.f; s_dx0[tid] = 0.f; }
    __syncthreads();

    for (int t = 0; t <= NT; ++t) {
        const int rs = t & 1, ps = (t + 1) & 1;
        if (layer == 0) {
            if (t < NT) {
                // ---- stage merged listA(rs): lo then hi (k ascending) ----
                int cLo = ld_cnt(&cnts[cidx(0, rs, bq, 0)]);
                int cHi = ld_cnt(&cnts[cidx(0, rs, bq, 1)]);
                int ntot = cLo + cHi, n1 = (ntot + 7) & ~7;
                const uint2* gLo = lists + lofs(0, rs, bq, 0);
                const uint2* gHi = lists + lofs(0, rs, bq, 1);
                if (tid < cLo)       s_l1[tid] = ld_ent(&gLo[tid]);
                else if (tid < ntot) s_l1[tid] = ld_ent(&gHi[tid - cLo]);
                else if (tid < n1)   s_l1[tid] = make_uint2(0u, 0u);
                if (tid < 6) {                        // input features, step t
                    float iv = s_x[2 * t], qv = s_x[2 * t + 1];
                    float amp = sqrtf(iv * iv + qv * qv);
                    float f;
                    if      (tid == 0) f = iv;
                    else if (tid == 1) f = qv;
                    else if (tid == 2) f = amp;
                    else if (tid == 3) f = amp * amp * amp;
                    else if (tid == 4) f = qv / amp;
                    else               f = iv / amp;
                    float dx = f - s_xp0[tid];
                    if (fabsf(dx) < THX) dx = 0.f; else s_xp0[tid] = f;
                    s_dx0[tid] = dx;
                }
                __syncthreads();                                     // S1
                // ---- MAC: unconditional, fresh block sums ----
                float aI = 0.f, aH = 0.f;
                #pragma unroll
                for (int f = 0; f < 6; ++f)           // dv==0 adds exact +0
                    aI += s_dx0[f] * wih0c[f * 1536];
                mac_pipe8(s_l1, n1, whh0c, aH);
                if (role != 3) carry += aI;           // (dm + sum_ih)
                if (role != 2) carry += aH;           // ... + sum_hh
                // ---- gates ----
                const int bl = lane & ~3;
                float ar  = __shfl(carry, bl + 0, 64);
                float az  = __shfl(carry, bl + 1, 64);
                float an  = __shfl(carry, bl + 2, 64);
                float anh = __shfl(carry, bl + 3, 64);
                float r = 1.f / (1.f + expf(-ar));
                float z = 1.f / (1.f + expf(-az));
                float n = tanhf(an + r * anh);
                h = (1.f - z) * n + z * h;
                // ---- deltas + dual compaction (A' = dh0, B' = dx1) ----
                float dA = h - hp;  if (fabsf(dA) < THH) dA = 0.f; else hp = h;
                float dB = h - xp1; if (fabsf(dB) < THX) dB = 0.f; else xp1 = h;
                bool nzA = (role == 0) && (dA != 0.f);
                bool nzB = (role == 0) && (dB != 0.f);
                unsigned long long mA = __ballot(nzA);
                unsigned long long mB = __ballot(nzB);
                if (lane == 0) { s_c1[wave] = __popcll(mA); s_c2[wave] = __popcll(mB); }
                __syncthreads();                                     // S2
                int baseA = 0, baseB = 0, totA = 0, totB = 0;
                #pragma unroll
                for (int w = 0; w < 16; ++w) {
                    int c1 = s_c1[w], c2 = s_c2[w];
                    baseA += (w < wave) ? c1 : 0;  totA += c1;
                    baseB += (w < wave) ? c2 : 0;  totB += c2;
                }
                uint2* outA = lists + lofs(0, ps, bq, half);
                uint2* outB = lists + lofs(1, ps, bq, half);
                unsigned long long below = (1ull << lane) - 1;
                if (nzA) outA[baseA + __popcll(mA & below)] =
                    make_uint2((unsigned)(uu * 6144u), __float_as_uint(dA));
                if (nzB) outB[baseB + __popcll(mB & below)] =
                    make_uint2((unsigned)(uu * 6144u), __float_as_uint(dB));
                if (tid == 0) {
                    cnts[cidx(0, ps, bq, half)] = totA;
                    cnts[cidx(1, ps, bq, half)] = totB;
                }
            }
        } else {
            if (t > 0) {
                // ---- L1 step t-1: stage merged listB(rs), listC(rs) ----
                int cBlo = ld_cnt(&cnts[cidx(1, rs, bq, 0)]);
                int cBhi = ld_cnt(&cnts[cidx(1, rs, bq, 1)]);
                int cClo = ld_cnt(&cnts[cidx(2, rs, bq, 0)]);
                int cChi = ld_cnt(&cnts[cidx(2, rs, bq, 1)]);
                int ntB = cBlo + cBhi, nB = (ntB + 7) & ~7;
                int ntC = cClo + cChi, nC = (ntC + 7) & ~7;
                const uint2* gBlo = lists + lofs(1, rs, bq, 0);
                const uint2* gBhi = lists + lofs(1, rs, bq, 1);
                const uint2* gClo = lists + lofs(2, rs, bq, 0);
                const uint2* gChi = lists + lofs(2, rs, bq, 1);
                if (tid < cBlo)      s_l1[tid] = ld_ent(&gBlo[tid]);
                else if (tid < ntB)  s_l1[tid] = ld_ent(&gBhi[tid - cBlo]);
                else if (tid < nB)   s_l1[tid] = make_uint2(0u, 0u);
                if (tid < cClo)      s_l2[tid] = ld_ent(&gClo[tid]);
                else if (tid < ntC)  s_l2[tid] = ld_ent(&gChi[tid - cClo]);
                else if (tid < nC)   s_l2[tid] = make_uint2(0u, 0u);
                __syncthreads();                                     // S1
                // ---- MAC: unconditional, fresh block sums ----
                float aI = 0.f, aH = 0.f;
                mac_pipe8(s_l1, nB, wih1c, aI);
                mac_pipe8(s_l2, nC, whh1c, aH);
                if (role != 3) carry += aI;
                if (role != 2) carry += aH;
                // ---- gates ----
                const int bl = lane & ~3;
                float ar  = __shfl(carry, bl + 0, 64);
                float az  = __shfl(carry, bl + 1, 64);
                float an  = __shfl(carry, bl + 2, 64);
                float anh = __shfl(carry, bl + 3, 64);
                float r = 1.f / (1.f + expf(-ar));
                float z = 1.f / (1.f + expf(-az));
                float n = tanhf(an + r * anh);
                h = (1.f - z) * n + z * h;
                // FC partials (role0 lanes), tree within wave, LDS across waves
                float p0 = (role == 0) ? h * wfc0 : 0.f;
                float p1 = (role == 0) ? h * wfc1 : 0.f;
                p0 += __shfl_down(p0, 4, 64);  p1 += __shfl_down(p1, 4, 64);
                p0 += __shfl_down(p0, 8, 64);  p1 += __shfl_down(p1, 8, 64);
                p0 += __shfl_down(p0, 16, 64); p1 += __shfl_down(p1, 16, 64);
                p0 += __shfl_down(p0, 32, 64); p1 += __shfl_down(p1, 32, 64);
                if (lane == 0) { s_fcp[wave][0] = p0; s_fcp[wave][1] = p1; }
                __syncthreads();
                if (tid == 0) {
                    float q0 = 0.f, q1 = 0.f;
                    #pragma unroll
                    for (int w = 0; w < 16; ++w) { q0 += s_fcp[w][0]; q1 += s_fcp[w][1]; }
                    float2* dst = (float2*)(ws_fc + (((size_t)bq * NT + (t - 1)) * 2 + half) * 2);
                    *dst = make_float2(q0, q1);
                }
            }
            if (t < NT) {
                // ---- dC publish (dh1 after step t-1) ----
                float dC = h - hp; if (fabsf(dC) < THH) dC = 0.f; else hp = h;
                bool nzC = (role == 0) && (dC != 0.f);
                unsigned long long mC = __ballot(nzC);
                if (lane == 0) s_c1[wave] = __popcll(mC);
                __syncthreads();                                     // S2
                int baseC = 0, totC = 0;
                #pragma unroll
                for (int w = 0; w < 16; ++w) {
                    int c = s_c1[w];
                    baseC += (w < wave) ? c : 0;  totC += c;
                }
                uint2* outC = lists + lofs(2, ps, bq, half);
                if (nzC) outC[baseC + __popcll(mC & ((1ull << lane) - 1))] =
                    make_uint2((unsigned)(uu * 6144u), __float_as_uint(dC));
                if (tid == 0) cnts[cidx(2, ps, bq, half)] = totC;
            }
        }
        // ---- quad barrier (padded flag, release add, relaxed poll) ----
        if (t < NT) {
            __syncthreads();   // drains this WG's global stores before arrival
            if (tid == 0) {
                __hip_atomic_fetch_add(&bars[bq * 64], 1, __ATOMIC_RELEASE,
                                       __HIP_MEMORY_SCOPE_AGENT);
                while (__hip_atomic_load(&bars[bq * 64], __ATOMIC_RELAXED,
                                         __HIP_MEMORY_SCOPE_AGENT) < 4 * (t + 1))
                    __builtin_amdgcn_s_sleep(8);
            }
            __syncthreads();
        }
    }
}

// ---- epilogue: deterministic FC reduction (lo half + hi half + bias) ----
__global__ void fc_reduce(const float* __restrict__ ws_fc,
                          const float* __restrict__ bfc,
                          float* __restrict__ out) {
    int idx = blockIdx.x * blockDim.x + threadIdx.x;   // (b*NT + t)
    if (idx < NB * NT) {
        const float2* p = (const float2*)(ws_fc + (size_t)idx * 4);
        out[idx * 2 + 0] = bfc[0] + p[0].x + p[1].x;
        out[idx * 2 + 1] = bfc[1] + p[0].y + p[1].y;
    }
}

// ---- safety-net fallback (ws too small): dense branchy loops, inline FC ----
__global__ __launch_bounds__(512)
void dgru_raw(const float* __restrict__ x,
              const float* __restrict__ wih0, const float* __restrict__ whh0,
              const float* __restrict__ wih1, const float* __restrict__ whh1,
              const float* __restrict__ bih0, const float* __restrict__ bhh0,
              const float* __restrict__ bih1, const float* __restrict__ bhh1,
              const float* __restrict__ wfc,  const float* __restrict__ bfc,
              float* __restrict__ out) {
    __shared__ float s_dx0[8];
    __shared__ float s_xp0[8];
    __shared__ float s_dh0[HID];
    __shared__ float s_dx1[HID];
    __shared__ float s_dh1[HID];
    __shared__ float s_part[16];

    const int j = threadIdx.x;
    const int b = blockIdx.x;
    float h0 = 0.f, h0p = 0.f, xp1 = 0.f, h1 = 0.f, h1p = 0.f;
    float cr0 = bih0[j] + bhh0[j];
    float cz0 = bih0[HID + j] + bhh0[HID + j];
    float cn0 = bih0[2*HID + j];
    float cnh0 = bhh0[2*HID + j];
    float cr1 = bih1[j] + bhh1[j];
    float cz1 = bih1[HID + j] + bhh1[HID + j];
    float cn1 = bih1[2*HID + j];
    float cnh1 = bhh1[2*HID + j];
    if (j < 8) { s_xp0[j] = 0.f; s_dx0[j] = 0.f; }
    const float wfc0 = wfc[j], wfc1 = wfc[HID + j];
    __syncthreads();

    for (int t = 0; t < NT; ++t) {
        float d = h0 - h0p;
        if (fabsf(d) < THH) d = 0.f; else h0p = h0;
        s_dh0[j] = d;
        if (j < 6) {
            float iv = x[(b * NT + t) * 2 + 0];
            float qv = x[(b * NT + t) * 2 + 1];
            float amp = sqrtf(iv * iv + qv * qv);
            float f;
            if      (j == 0) f = iv;
            else if (j == 1) f = qv;
            else if (j == 2) f = amp;
            else if (j == 3) f = amp * amp * amp;
            else if (j == 4) f = qv / amp;
            else             f = iv / amp;
            float dx = f - s_xp0[j];
            if (fabsf(dx) < THX) dx = 0.f; else s_xp0[j] = f;
            s_dx0[j] = dx;
        }
        __syncthreads();
        {
            float ar = cr0, az = cz0, an = cn0, anh = cnh0;
            #pragma unroll
            for (int f = 0; f < 6; ++f) {
                float dv = s_dx0[f];
                ar += dv * wih0[j * 6 + f];
                az += dv * wih0[(HID + j) * 6 + f];
                an += dv * wih0[(2*HID + j) * 6 + f];
            }
            for (int k = 0; k < HID; ++k) {
                float dv = s_dh0[k];
                if (dv != 0.f) {
                    ar  += dv * whh0[j * HID + k];
                    az  += dv * whh0[(HID + j) * HID + k];
                    anh += dv * whh0[(2*HID + j) * HID + k];
                }
            }
            cr0 = ar; cz0 = az; cn0 = an; cnh0 = anh;
            float r = 1.f / (1.f + expf(-ar));
            float z = 1.f / (1.f + expf(-az));
            float n = tanhf(an + r * anh);
            h0 = (1.f - z) * n + z * h0;
        }
        float dxv = h0 - xp1;
        if (fabsf(dxv) < THX) dxv = 0.f; else xp1 = h0;
        s_dx1[j] = dxv;
        float dhv = h1 - h1p;
        if (fabsf(dhv) < THH) dhv = 0.f; else h1p = h1;
        s_dh1[j] = dhv;
        __syncthreads();
        {
            float ar = cr1, az = cz1, an = cn1, anh = cnh1;
            for (int k = 0; k < HID; ++k) {
                float dv = s_dx1[k];
                if (dv != 0.f) {
                    ar += dv * wih1[j * HID + k];
                    az += dv * wih1[(HID + j) * HID + k];
                    an += dv * wih1[(2*HID + j) * HID + k];
                }
            }
            for (int k = 0; k < HID; ++k) {
                float dv = s_dh1[k];
                if (dv != 0.f) {
                    ar  += dv * whh1[j * HID + k];
                    az  += dv * whh1[(HID + j) * HID + k];
                    anh += dv * whh1[(2*HID + j) * HID + k];
                }
            }
            cr1 = ar; cz1 = az; cn1 = an; cnh1 = anh;
            float r = 1.f / (1.f + expf(-ar));
            float z = 1.f / (1.f + expf(-az));
            float n = tanhf(an + r * anh);
            h1 = (1.f - z) * n + z * h1;
        }
        float p0 = h1 * wfc0, p1 = h1 * wfc1;
        #pragma unroll
        for (int off = 32; off > 0; off >>= 1) {
            p0 += __shfl_down(p0, off, 64);
            p1 += __shfl_down(p1, off, 64);
        }
        if ((j & 63) == 0) { s_part[(j >> 6) * 2] = p0; s_part[(j >> 6) * 2 + 1] = p1; }
        __syncthreads();
        if (j == 0) {
            float o0 = bfc[0], o1 = bfc[1];
            #pragma unroll
            for (int w = 0; w < 8; ++w) { o0 += s_part[w * 2]; o1 += s_part[w * 2 + 1]; }
            out[(b * NT + t) * 2 + 0] = o0;
            out[(b * NT + t) * 2 + 1] = o1;
        }
    }
}

extern "C" void kernel_launch(void* const* d_in, const int* in_sizes, int n_in,
                              void* d_out, int out_size, void* d_ws, size_t ws_size,
                              hipStream_t stream) {
    const float* x    = (const float*)d_in[0];
    // d_in[1] = h_0 : reference zero-inits h, input unused
    const float* wih0 = (const float*)d_in[2];
    const float* whh0 = (const float*)d_in[3];
    const float* bih0 = (const float*)d_in[4];
    const float* bhh0 = (const float*)d_in[5];
    const float* wih1 = (const float*)d_in[6];
    const float* whh1 = (const float*)d_in[7];
    const float* bih1 = (const float*)d_in[8];
    const float* bhh1 = (const float*)d_in[9];
    const float* wfc  = (const float*)d_in[10];
    const float* bfc  = (const float*)d_in[11];
    float* out = (float*)d_out;

    const size_t MAT3    = (size_t)HID * 1536 * sizeof(float);     // 3 MiB each
    const size_t o_ih0   = 0;                                       // 36,864 B
    const size_t o_hh0   = 6 * 1536 * sizeof(float);
    const size_t o_ih1   = o_hh0 + MAT3;
    const size_t o_hh1   = o_ih1 + MAT3;
    const size_t o_lists = o_hh1 + MAT3;
    const size_t LISTS_B = (size_t)3 * 2 * NB * 2 * 256 * 8;        // 1.5 MiB
    const size_t o_cnts  = o_lists + LISTS_B;
    const size_t o_bars  = o_cnts + (size_t)3 * 2 * NB * 2 * sizeof(int);
    const size_t o_fc    = o_bars + (size_t)NB * 64 * sizeof(int);
    const size_t FCB     = (size_t)NB * NT * 4 * sizeof(float);     // 1 MiB
    const size_t need    = o_fc + FCB;                              // ~12 MiB

    if (ws_size >= need) {
        float* wt_ih0 = (float*)((char*)d_ws + o_ih0);
        float* wt_hh0 = (float*)((char*)d_ws + o_hh0);
        float* wt_ih1 = (float*)((char*)d_ws + o_ih1);
        float* wt_hh1 = (float*)((char*)d_ws + o_hh1);
        uint2* g_lists = (uint2*)((char*)d_ws + o_lists);
        int*   g_cnts  = (int*)((char*)d_ws + o_cnts);
        int*   g_bars  = (int*)((char*)d_ws + o_bars);
        float* g_fc    = (float*)((char*)d_ws + o_fc);

        pack_ih0<<<(6 * HID + 255) / 256, 256, 0, stream>>>(wih0, wt_ih0);
        pack_h3<<<(HID * HID + 255) / 256, 256, 0, stream>>>(whh0, wt_hh0);
        pack_h3<<<(HID * HID + 255) / 256, 256, 0, stream>>>(wih1, wt_ih1);
        pack_h3<<<(HID * HID + 255) / 256, 256, 0, stream>>>(whh1, wt_hh1);
        init_ws<<<4, 1024, 0, stream>>>(g_cnts, g_bars);
        dgru_split<<<4 * NB, 1024, 0, stream>>>(x, wt_ih0, wt_hh0, wt_ih1, wt_hh1,
                                                bih0, bhh0, bih1, bhh1, wfc,
                                                g_lists, g_cnts, g_bars, g_fc);
        fc_reduce<<<(NB * NT + 255) / 256, 256, 0, stream>>>(g_fc, bfc, out);
    } else {
        dgru_raw<<<NB, HID, 0, stream>>>(x, wih0, whh0, wih1, whh1,
                                         bih0, bhh0, bih1, bhh1, wfc, bfc, out);
    }
}

// Round 14
// 31118.381 us; speedup vs baseline: 2.4984x; 1.7424x over previous
//
#include <hip/hip_runtime.h>

#define HID 512
#define NB  64
#define NT  1024
#define THX 0.1f
#define THH 0.05f

// ---- prep: pack W_ih_l0 [1536][6] f32 -> [6][512]{r,z,n} float3 ----
__global__ void pack_ih0(const float* __restrict__ src, float* __restrict__ dst) {
    int idx = blockIdx.x * blockDim.x + threadIdx.x;
    if (idx < 6 * HID) {
        int f = idx / HID, j = idx % HID;
        dst[f * 1536 + j * 3 + 0] = src[(0 * HID + j) * 6 + f];
        dst[f * 1536 + j * 3 + 1] = src[(1 * HID + j) * 6 + f];
        dst[f * 1536 + j * 3 + 2] = src[(2 * HID + j) * 6 + f];
    }
}

// ---- prep: pack a [1536][512] f32 matrix -> [512(k)][512(j)]{r,z,n} float3 ----
// third slot = row 2H+j (the n / nh weight) -> one dwordx3 load serves all gates.
__global__ void pack_h3(const float* __restrict__ src, float* __restrict__ dst) {
    int idx = blockIdx.x * blockDim.x + threadIdx.x;
    if (idx < HID * HID) {
        int k = idx / HID, j = idx % HID;
        dst[k * 1536 + j * 3 + 0] = src[(0 * HID + j) * HID + k];
        dst[k * 1536 + j * 3 + 1] = src[(1 * HID + j) * HID + k];
        dst[k * 1536 + j * 3 + 2] = src[(2 * HID + j) * HID + k];
    }
}

// ---- init: zero list counts + padded barrier flags ----
__global__ void init_ws(int* __restrict__ cnts, int* __restrict__ bars) {
    int i = blockIdx.x * blockDim.x + threadIdx.x;
    if (i < 3 * 2 * NB * 2) cnts[i] = 0;
    if (i < NB * 64) bars[i] = 0;
}

__device__ __forceinline__ int cidx(int kind, int slot, int b, int half) {
    return ((kind * 2 + slot) * NB + b) * 2 + half;
}
__device__ __forceinline__ int lofs(int kind, int slot, int b, int half) {
    return (((kind * 2 + slot) * NB + b) * 2 + half) * 256;   // uint2 units
}

// ---- coherent relaxed loads (no fences -> L2 weight lines stay resident) ----
__device__ __forceinline__ int ld_cnt(const int* p) {
    return __hip_atomic_load(p, __ATOMIC_RELAXED, __HIP_MEMORY_SCOPE_AGENT);
}
__device__ __forceinline__ uint2 ld_ent(const uint2* p) {
    unsigned long long r = __hip_atomic_load((const unsigned long long*)p,
                             __ATOMIC_RELAXED, __HIP_MEMORY_SCOPE_AGENT);
    return make_uint2((unsigned)r, (unsigned)(r >> 32));
}

// ---- depth-8 pipelined slot MAC: entries sl[4*j], j < m (m multiple of 8) ----
// Per entry per thread: ds_read_b64 + 64-bit add + global_load_dwordx3 + 3 fma.
// Only ONE slot (4 waves) loads each entry: 4 VMEM instrs/entry vs r10's 16.
// e.x carries the pre-multiplied byte row offset (k*6144).
__device__ __forceinline__ void mac3_pipe8(const uint2* __restrict__ sl, int m,
                                           const char* __restrict__ cb,
                                           float& a0, float& a1, float& a2) {
    if (m <= 0) return;
    float  v0, v1, v2, v3, v4, v5, v6, v7;
    float3 w0, w1, w2, w3, w4, w5, w6, w7;
#define PISS(S, J) { uint2 e_ = sl[4 * (J)]; v##S = __uint_as_float(e_.y); \
    w##S = *(const float3*)(cb + e_.x); }
#define PCON(S, JN, MORE) { float3 W_ = w##S; float V_ = v##S; \
    if (MORE) PISS(S, (JN)) \
    a0 += V_ * W_.x; a1 += V_ * W_.y; a2 += V_ * W_.z; }
    PISS(0,0) PISS(1,1) PISS(2,2) PISS(3,3)
    PISS(4,4) PISS(5,5) PISS(6,6) PISS(7,7)
    #pragma unroll 1
    for (int j = 0; j < m; j += 8) {
        const int jn = j + 8;
        const bool more = jn < m;
        PCON(0,jn+0,more) PCON(1,jn+1,more) PCON(2,jn+2,more) PCON(3,jn+3,more)
        PCON(4,jn+4,more) PCON(5,jn+5,more) PCON(6,jn+6,more) PCON(7,jn+7,more)
    }
#undef PISS
#undef PCON
}

// ---- main kernel: 256 WGs = 64 batches x {L0,L1} x {half lo,hi} ----
// 1024 threads = 4 entry-slots x 256 units. Slot s handles entries i==s mod 4,
// loading the unit's full float3 row slice. Slot partials merged in fixed slot
// order (block reassociation validated r12/r13). Unit phase = first 4 waves.
__global__ __launch_bounds__(1024, 4)
void dgru_split(const float* __restrict__ x,
                const float* __restrict__ wih0p,   // [6][512] float3
                const float* __restrict__ whh0p,   // [512][512] float3
                const float* __restrict__ wih1p,
                const float* __restrict__ whh1p,
                const float* __restrict__ bih0, const float* __restrict__ bhh0,
                const float* __restrict__ bih1, const float* __restrict__ bhh1,
                const float* __restrict__ wfc,
                uint2* __restrict__ lists, int* __restrict__ cnts,
                int* __restrict__ bars, float* __restrict__ ws_fc) {
    __shared__ float s_x[2 * NT];                  // 8 KB (L0 only)
    __shared__ float s_dx0[8];
    __shared__ float s_xp0[8];
    __shared__ uint2 s_l1[544];
    __shared__ uint2 s_l2[544];
    __shared__ float s_pp[4][6][256];              // 24 KB slot partials
    __shared__ int   s_c1[4], s_c2[4];
    __shared__ float s_fcp[4][2];

    const int wgid  = blockIdx.x;
    const int bq    = wgid >> 2;
    const int layer = (wgid >> 1) & 1;
    const int half  = wgid & 1;
    const int tid   = threadIdx.x;
    const int lane  = tid & 63;
    const int wave  = tid >> 6;
    const int u     = tid & 255;
    const int slot  = tid >> 8;                    // 0..3, wave-uniform
    const int uu    = half * 256 + u;

    const float* bih = layer ? bih1 : bih0;
    const float* bhh = layer ? bhh1 : bhh0;

    // carries + unit state live in the unit-phase threads (tid<256)
    float cr = 0.f, cz = 0.f, cn = 0.f, cnh = 0.f;
    float h = 0.f, hp = 0.f, xp1 = 0.f;
    float wfc0 = 0.f, wfc1 = 0.f;
    if (tid < 256) {
        cr  = bih[uu]         + bhh[uu];
        cz  = bih[HID + uu]   + bhh[HID + uu];
        cn  = bih[2*HID + uu];
        cnh = bhh[2*HID + uu];
        wfc0 = wfc[uu]; wfc1 = wfc[HID + uu];
    }

    // per-thread column base (12 B per unit), wave-uniform slot offset on lists
    const char* c_ih0 = (const char*)wih0p + uu * 12;
    const char* c_hh  = (const char*)(layer ? whh1p : whh0p) + uu * 12;
    const char* c_ih1 = (const char*)wih1p + uu * 12;

    if (layer == 0)
        for (int i = tid; i < 2 * NT; i += 1024) s_x[i] = x[bq * 2 * NT + i];
    if (tid < 8) { s_xp0[tid] = 0.f; s_dx0[tid] = 0.f; }
    __syncthreads();

    for (int t = 0; t <= NT; ++t) {
        const int rs = t & 1, ps = (t + 1) & 1;
        if (layer == 0) {
            if (t < NT) {
                // ---- stage merged listA(rs): lo then hi (k ascending) ----
                int cLo = ld_cnt(&cnts[cidx(0, rs, bq, 0)]);
                int cHi = ld_cnt(&cnts[cidx(0, rs, bq, 1)]);
                int ntot = cLo + cHi, n1 = (ntot + 31) & ~31;
                const uint2* gLo = lists + lofs(0, rs, bq, 0);
                const uint2* gHi = lists + lofs(0, rs, bq, 1);
                if (tid < cLo)       s_l1[tid] = ld_ent(&gLo[tid]);
                else if (tid < ntot) s_l1[tid] = ld_ent(&gHi[tid - cLo]);
                else if (tid < n1)   s_l1[tid] = make_uint2(0u, 0u);
                if (tid < 6) {                        // input features, step t
                    float iv = s_x[2 * t], qv = s_x[2 * t + 1];
                    float amp = sqrtf(iv * iv + qv * qv);
                    float f;
                    if      (tid == 0) f = iv;
                    else if (tid == 1) f = qv;
                    else if (tid == 2) f = amp;
                    else if (tid == 3) f = amp * amp * amp;
                    else if (tid == 4) f = qv / amp;
                    else               f = iv / amp;
                    float dx = f - s_xp0[tid];
                    if (fabsf(dx) < THX) dx = 0.f; else s_xp0[tid] = f;
                    s_dx0[tid] = dx;
                }
                __syncthreads();                                     // S1
                // ---- slot MAC over whh0 (r,z,nh) ----
                float hR = 0.f, hZ = 0.f, hNH = 0.f;
                mac3_pipe8(s_l1 + slot, n1 >> 2, c_hh, hR, hZ, hNH);
                s_pp[slot][0][u] = hR;
                s_pp[slot][1][u] = hZ;
                s_pp[slot][2][u] = hNH;
                if (slot == 0) {                      // dense ih0 (6 features)
                    float iR = 0.f, iZ = 0.f, iN = 0.f;
                    #pragma unroll
                    for (int f = 0; f < 6; ++f) {     // dv==0 adds exact +0
                        float dv = s_dx0[f];
                        float3 w = *(const float3*)(c_ih0 + f * 6144);
                        iR += dv * w.x; iZ += dv * w.y; iN += dv * w.z;
                    }
                    s_pp[0][3][u] = iR;
                    s_pp[0][4][u] = iZ;
                    s_pp[0][5][u] = iN;
                }
                __syncthreads();                                     // S2
                // ---- unit phase: merge (slot order), gates, deltas ----
                float dA = 0.f, dB = 0.f;
                bool nzA = false, nzB = false;
                unsigned long long mA = 0, mB = 0;
                if (tid < 256) {
                    float mhR = s_pp[0][0][u] + s_pp[1][0][u] + s_pp[2][0][u] + s_pp[3][0][u];
                    float mhZ = s_pp[0][1][u] + s_pp[1][1][u] + s_pp[2][1][u] + s_pp[3][1][u];
                    float mhN = s_pp[0][2][u] + s_pp[1][2][u] + s_pp[2][2][u] + s_pp[3][2][u];
                    float ar  = cr + s_pp[0][3][u] + mhR;   // carry + mac_x + mac_h
                    float az  = cz + s_pp[0][4][u] + mhZ;
                    float an  = cn + s_pp[0][5][u];
                    float anh = cnh + mhN;
                    cr = ar; cz = az; cn = an; cnh = anh;
                    float r = 1.f / (1.f + expf(-ar));
                    float z = 1.f / (1.f + expf(-az));
                    float n = tanhf(an + r * anh);
                    h = (1.f - z) * n + z * h;
                    dA = h - hp;  if (fabsf(dA) < THH) dA = 0.f; else hp = h;
                    dB = h - xp1; if (fabsf(dB) < THX) dB = 0.f; else xp1 = h;
                    nzA = dA != 0.f; nzB = dB != 0.f;
                    mA = __ballot(nzA); mB = __ballot(nzB);
                    if (lane == 0) { s_c1[wave] = __popcll(mA); s_c2[wave] = __popcll(mB); }
                }
                __syncthreads();                                     // S3
                if (tid < 256) {
                    int baseA = 0, baseB = 0, totA = 0, totB = 0;
                    #pragma unroll
                    for (int w = 0; w < 4; ++w) {
                        baseA += (w < wave) ? s_c1[w] : 0;  totA += s_c1[w];
                        baseB += (w < wave) ? s_c2[w] : 0;  totB += s_c2[w];
                    }
                    uint2* outA = lists + lofs(0, ps, bq, half);
                    uint2* outB = lists + lofs(1, ps, bq, half);
                    unsigned long long below = (1ull << lane) - 1;
                    if (nzA) outA[baseA + __popcll(mA & below)] =
                        make_uint2((unsigned)(uu * 6144u), __float_as_uint(dA));
                    if (nzB) outB[baseB + __popcll(mB & below)] =
                        make_uint2((unsigned)(uu * 6144u), __float_as_uint(dB));
                    if (tid == 0) {
                        cnts[cidx(0, ps, bq, half)] = totA;
                        cnts[cidx(1, ps, bq, half)] = totB;
                    }
                }
            }
        } else {
            if (t > 0) {
                // ---- L1 step t-1: stage merged listB(rs), listC(rs) ----
                int cBlo = ld_cnt(&cnts[cidx(1, rs, bq, 0)]);
                int cBhi = ld_cnt(&cnts[cidx(1, rs, bq, 1)]);
                int cClo = ld_cnt(&cnts[cidx(2, rs, bq, 0)]);
                int cChi = ld_cnt(&cnts[cidx(2, rs, bq, 1)]);
                int ntB = cBlo + cBhi, nB = (ntB + 31) & ~31;
                int ntC = cClo + cChi, nC = (ntC + 31) & ~31;
                const uint2* gBlo = lists + lofs(1, rs, bq, 0);
                const uint2* gBhi = lists + lofs(1, rs, bq, 1);
                const uint2* gClo = lists + lofs(2, rs, bq, 0);
                const uint2* gChi = lists + lofs(2, rs, bq, 1);
                if (tid < cBlo)      s_l1[tid] = ld_ent(&gBlo[tid]);
                else if (tid < ntB)  s_l1[tid] = ld_ent(&gBhi[tid - cBlo]);
                else if (tid < nB)   s_l1[tid] = make_uint2(0u, 0u);
                if (tid < cClo)      s_l2[tid] = ld_ent(&gClo[tid]);
                else if (tid < ntC)  s_l2[tid] = ld_ent(&gChi[tid - cClo]);
                else if (tid < nC)   s_l2[tid] = make_uint2(0u, 0u);
                __syncthreads();                                     // S1
                // ---- slot MAC: listB over wih1 (r,z,n), listC over whh1 ----
                float iR = 0.f, iZ = 0.f, iN = 0.f;
                float hR = 0.f, hZ = 0.f, hNH = 0.f;
                mac3_pipe8(s_l1 + slot, nB >> 2, c_ih1, iR, iZ, iN);
                mac3_pipe8(s_l2 + slot, nC >> 2, c_hh,  hR, hZ, hNH);
                s_pp[slot][0][u] = iR;
                s_pp[slot][1][u] = iZ;
                s_pp[slot][2][u] = iN;
                s_pp[slot][3][u] = hR;
                s_pp[slot][4][u] = hZ;
                s_pp[slot][5][u] = hNH;
                __syncthreads();                                     // S2
                // ---- unit phase ----
                float dC = 0.f; bool nzC = false; unsigned long long mC = 0;
                if (tid < 256) {
                    float xiR = s_pp[0][0][u] + s_pp[1][0][u] + s_pp[2][0][u] + s_pp[3][0][u];
                    float xiZ = s_pp[0][1][u] + s_pp[1][1][u] + s_pp[2][1][u] + s_pp[3][1][u];
                    float xiN = s_pp[0][2][u] + s_pp[1][2][u] + s_pp[2][2][u] + s_pp[3][2][u];
                    float mhR = s_pp[0][3][u] + s_pp[1][3][u] + s_pp[2][3][u] + s_pp[3][3][u];
                    float mhZ = s_pp[0][4][u] + s_pp[1][4][u] + s_pp[2][4][u] + s_pp[3][4][u];
                    float mhN = s_pp[0][5][u] + s_pp[1][5][u] + s_pp[2][5][u] + s_pp[3][5][u];
                    float ar  = cr + xiR + mhR;
                    float az  = cz + xiZ + mhZ;
                    float an  = cn + xiN;
                    float anh = cnh + mhN;
                    cr = ar; cz = az; cn = an; cnh = anh;
                    float r = 1.f / (1.f + expf(-ar));
                    float z = 1.f / (1.f + expf(-az));
                    float n = tanhf(an + r * anh);
                    h = (1.f - z) * n + z * h;
                    float p0 = h * wfc0, p1 = h * wfc1;
                    #pragma unroll
                    for (int off = 32; off > 0; off >>= 1) {
                        p0 += __shfl_down(p0, off, 64);
                        p1 += __shfl_down(p1, off, 64);
                    }
                    if (lane == 0) { s_fcp[wave][0] = p0; s_fcp[wave][1] = p1; }
                    dC = h - hp; if (fabsf(dC) < THH) dC = 0.f; else hp = h;
                    nzC = dC != 0.f;
                    mC = __ballot(nzC);
                    if (lane == 0) s_c1[wave] = __popcll(mC);
                }
                __syncthreads();                                     // S3
                if (tid < 256) {
                    int baseC = 0, totC = 0;
                    #pragma unroll
                    for (int w = 0; w < 4; ++w) {
                        baseC += (w < wave) ? s_c1[w] : 0;  totC += s_c1[w];
                    }
                    uint2* outC = lists + lofs(2, ps, bq, half);
                    unsigned long long below = (1ull << lane) - 1;
                    if (nzC) outC[baseC + __popcll(mC & below)] =
                        make_uint2((unsigned)(uu * 6144u), __float_as_uint(dC));
                    if (tid == 0) {
                        cnts[cidx(2, ps, bq, half)] = totC;
                        float2* dst = (float2*)(ws_fc +
                            (((size_t)bq * NT + (t - 1)) * 2 + half) * 2);
                        *dst = make_float2(s_fcp[0][0] + s_fcp[1][0] + s_fcp[2][0] + s_fcp[3][0],
                                           s_fcp[0][1] + s_fcp[1][1] + s_fcp[2][1] + s_fcp[3][1]);
                    }
                }
            } else {
                // t==0: publish empty dh1 list for step 0
                if (tid == 0) cnts[cidx(2, ps, bq, half)] = 0;
            }
        }
        // ---- quad barrier (padded flag, release add, relaxed poll) ----
        if (t < NT) {
            __syncthreads();   // drains this WG's global stores before arrival
            if (tid == 0) {
                __hip_atomic_fetch_add(&bars[bq * 64], 1, __ATOMIC_RELEASE,
                                       __HIP_MEMORY_SCOPE_AGENT);
                while (__hip_atomic_load(&bars[bq * 64], __ATOMIC_RELAXED,
                                         __HIP_MEMORY_SCOPE_AGENT) < 4 * (t + 1))
                    __builtin_amdgcn_s_sleep(8);
            }
            __syncthreads();
        }
    }
}

// ---- epilogue: deterministic FC reduction (lo half + hi half + bias) ----
__global__ void fc_reduce(const float* __restrict__ ws_fc,
                          const float* __restrict__ bfc,
                          float* __restrict__ out) {
    int idx = blockIdx.x * blockDim.x + threadIdx.x;   // (b*NT + t)
    if (idx < NB * NT) {
        const float2* p = (const float2*)(ws_fc + (size_t)idx * 4);
        out[idx * 2 + 0] = bfc[0] + p[0].x + p[1].x;
        out[idx * 2 + 1] = bfc[1] + p[0].y + p[1].y;
    }
}

// ---- safety-net fallback (ws too small): dense branchy loops, inline FC ----
__global__ __launch_bounds__(512)
void dgru_raw(const float* __restrict__ x,
              const float* __restrict__ wih0, const float* __restrict__ whh0,
              const float* __restrict__ wih1, const float* __restrict__ whh1,
              const float* __restrict__ bih0, const float* __restrict__ bhh0,
              const float* __restrict__ bih1, const float* __restrict__ bhh1,
              const float* __restrict__ wfc,  const float* __restrict__ bfc,
              float* __restrict__ out) {
    __shared__ float s_dx0[8];
    __shared__ float s_xp0[8];
    __shared__ float s_dh0[HID];
    __shared__ float s_dx1[HID];
    __shared__ float s_dh1[HID];
    __shared__ float s_part[16];

    const int j = threadIdx.x;
    const int b = blockIdx.x;
    float h0 = 0.f, h0p = 0.f, xp1 = 0.f, h1 = 0.f, h1p = 0.f;
    float cr0 = bih0[j] + bhh0[j];
    float cz0 = bih0[HID + j] + bhh0[HID + j];
    float cn0 = bih0[2*HID + j];
    float cnh0 = bhh0[2*HID + j];
    float cr1 = bih1[j] + bhh1[j];
    float cz1 = bih1[HID + j] + bhh1[HID + j];
    float cn1 = bih1[2*HID + j];
    float cnh1 = bhh1[2*HID + j];
    if (j < 8) { s_xp0[j] = 0.f; s_dx0[j] = 0.f; }
    const float wfc0 = wfc[j], wfc1 = wfc[HID + j];
    __syncthreads();

    for (int t = 0; t < NT; ++t) {
        float d = h0 - h0p;
        if (fabsf(d) < THH) d = 0.f; else h0p = h0;
        s_dh0[j] = d;
        if (j < 6) {
            float iv = x[(b * NT + t) * 2 + 0];
            float qv = x[(b * NT + t) * 2 + 1];
            float amp = sqrtf(iv * iv + qv * qv);
            float f;
            if      (j == 0) f = iv;
            else if (j == 1) f = qv;
            else if (j == 2) f = amp;
            else if (j == 3) f = amp * amp * amp;
            else if (j == 4) f = qv / amp;
            else             f = iv / amp;
            float dx = f - s_xp0[j];
            if (fabsf(dx) < THX) dx = 0.f; else s_xp0[j] = f;
            s_dx0[j] = dx;
        }
        __syncthreads();
        {
            float ar = cr0, az = cz0, an = cn0, anh = cnh0;
            #pragma unroll
            for (int f = 0; f < 6; ++f) {
                float dv = s_dx0[f];
                ar += dv * wih0[j * 6 + f];
                az += dv * wih0[(HID + j) * 6 + f];
                an += dv * wih0[(2*HID + j) * 6 + f];
            }
            for (int k = 0; k < HID; ++k) {
                float dv = s_dh0[k];
                if (dv != 0.f) {
                    ar  += dv * whh0[j * HID + k];
                    az  += dv * whh0[(HID + j) * HID + k];
                    anh += dv * whh0[(2*HID + j) * HID + k];
                }
            }
            cr0 = ar; cz0 = az; cn0 = an; cnh0 = anh;
            float r = 1.f / (1.f + expf(-ar));
            float z = 1.f / (1.f + expf(-az));
            float n = tanhf(an + r * anh);
            h0 = (1.f - z) * n + z * h0;
        }
        float dxv = h0 - xp1;
        if (fabsf(dxv) < THX) dxv = 0.f; else xp1 = h0;
        s_dx1[j] = dxv;
        float dhv = h1 - h1p;
        if (fabsf(dhv) < THH) dhv = 0.f; else h1p = h1;
        s_dh1[j] = dhv;
        __syncthreads();
        {
            float ar = cr1, az = cz1, an = cn1, anh = cnh1;
            for (int k = 0; k < HID; ++k) {
                float dv = s_dx1[k];
                if (dv != 0.f) {
                    ar += dv * wih1[j * HID + k];
                    az += dv * wih1[(HID + j) * HID + k];
                    an += dv * wih1[(2*HID + j) * HID + k];
                }
            }
            for (int k = 0; k < HID; ++k) {
                float dv = s_dh1[k];
                if (dv != 0.f) {
                    ar  += dv * whh1[j * HID + k];
                    az  += dv * whh1[(HID + j) * HID + k];
                    anh += dv * whh1[(2*HID + j) * HID + k];
                }
            }
            cr1 = ar; cz1 = az; cn1 = an; cnh1 = anh;
            float r = 1.f / (1.f + expf(-ar));
            float z = 1.f / (1.f + expf(-az));
            float n = tanhf(an + r * anh);
            h1 = (1.f - z) * n + z * h1;
        }
        float p0 = h1 * wfc0, p1 = h1 * wfc1;
        #pragma unroll
        for (int off = 32; off > 0; off >>= 1) {
            p0 += __shfl_down(p0, off, 64);
            p1 += __shfl_down(p1, off, 64);
        }
        if ((j & 63) == 0) { s_part[(j >> 6) * 2] = p0; s_part[(j >> 6) * 2 + 1] = p1; }
        __syncthreads();
        if (j == 0) {
            float o0 = bfc[0], o1 = bfc[1];
            #pragma unroll
            for (int w = 0; w < 8; ++w) { o0 += s_part[w * 2]; o1 += s_part[w * 2 + 1]; }
            out[(b * NT + t) * 2 + 0] = o0;
            out[(b * NT + t) * 2 + 1] = o1;
        }
    }
}

extern "C" void kernel_launch(void* const* d_in, const int* in_sizes, int n_in,
                              void* d_out, int out_size, void* d_ws, size_t ws_size,
                              hipStream_t stream) {
    const float* x    = (const float*)d_in[0];
    // d_in[1] = h_0 : reference zero-inits h, input unused
    const float* wih0 = (const float*)d_in[2];
    const float* whh0 = (const float*)d_in[3];
    const float* bih0 = (const float*)d_in[4];
    const float* bhh0 = (const float*)d_in[5];
    const float* wih1 = (const float*)d_in[6];
    const float* whh1 = (const float*)d_in[7];
    const float* bih1 = (const float*)d_in[8];
    const float* bhh1 = (const float*)d_in[9];
    const float* wfc  = (const float*)d_in[10];
    const float* bfc  = (const float*)d_in[11];
    float* out = (float*)d_out;

    const size_t MAT3    = (size_t)HID * 1536 * sizeof(float);     // 3 MiB each
    const size_t o_ih0   = 0;                                       // 36,864 B
    const size_t o_hh0   = 6 * 1536 * sizeof(float);
    const size_t o_ih1   = o_hh0 + MAT3;
    const size_t o_hh1   = o_ih1 + MAT3;
    const size_t o_lists = o_hh1 + MAT3;
    const size_t LISTS_B = (size_t)3 * 2 * NB * 2 * 256 * 8;        // 1.5 MiB
    const size_t o_cnts  = o_lists + LISTS_B;
    const size_t o_bars  = o_cnts + (size_t)3 * 2 * NB * 2 * sizeof(int);
    const size_t o_fc    = o_bars + (size_t)NB * 64 * sizeof(int);
    const size_t FCB     = (size_t)NB * NT * 4 * sizeof(float);     // 1 MiB
    const size_t need    = o_fc + FCB;                              // ~12 MiB

    if (ws_size >= need) {
        float* wt_ih0 = (float*)((char*)d_ws + o_ih0);
        float* wt_hh0 = (float*)((char*)d_ws + o_hh0);
        float* wt_ih1 = (float*)((char*)d_ws + o_ih1);
        float* wt_hh1 = (float*)((char*)d_ws + o_hh1);
        uint2* g_lists = (uint2*)((char*)d_ws + o_lists);
        int*   g_cnts  = (int*)((char*)d_ws + o_cnts);
        int*   g_bars  = (int*)((char*)d_ws + o_bars);
        float* g_fc    = (float*)((char*)d_ws + o_fc);

        pack_ih0<<<(6 * HID + 255) / 256, 256, 0, stream>>>(wih0, wt_ih0);
        pack_h3<<<(HID * HID + 255) / 256, 256, 0, stream>>>(whh0, wt_hh0);
        pack_h3<<<(HID * HID + 255) / 256, 256, 0, stream>>>(wih1, wt_ih1);
        pack_h3<<<(HID * HID + 255) / 256, 256, 0, stream>>>(whh1, wt_hh1);
        init_ws<<<4, 1024, 0, stream>>>(g_cnts, g_bars);
        dgru_split<<<4 * NB, 1024, 0, stream>>>(x, wt_ih0, wt_hh0, wt_ih1, wt_hh1,
                                                bih0, bhh0, bih1, bhh1, wfc,
                                                g_lists, g_cnts, g_bars, g_fc);
        fc_reduce<<<(NB * NT + 255) / 256, 256, 0, stream>>>(g_fc, bfc, out);
    } else {
        dgru_raw<<<NB, HID, 0, stream>>>(x, wih0, whh0, wih1, whh1,
                                         bih0, bhh0, bih1, bhh1, wfc, bfc, out);
    }
}

// Round 15
// 30701.147 us; speedup vs baseline: 2.5324x; 1.0136x over previous
//
#include <hip/hip_runtime.h>

#define HID 512
#define NB  64
#define NT  1024
#define THX 0.1f
#define THH 0.05f

// ---- prep: pack W_ih_l0 [1536][6] f32 -> [6][512]{r,z,n} float3 ----
__global__ void pack_ih0(const float* __restrict__ src, float* __restrict__ dst) {
    int idx = blockIdx.x * blockDim.x + threadIdx.x;
    if (idx < 6 * HID) {
        int f = idx / HID, j = idx % HID;
        dst[f * 1536 + j * 3 + 0] = src[(0 * HID + j) * 6 + f];
        dst[f * 1536 + j * 3 + 1] = src[(1 * HID + j) * 6 + f];
        dst[f * 1536 + j * 3 + 2] = src[(2 * HID + j) * 6 + f];
    }
}

// ---- prep: pack a [1536][512] f32 matrix -> [512(k)][512(j)]{r,z,n} float3 ----
__global__ void pack_h3(const float* __restrict__ src, float* __restrict__ dst) {
    int idx = blockIdx.x * blockDim.x + threadIdx.x;
    if (idx < HID * HID) {
        int k = idx / HID, j = idx % HID;
        dst[k * 1536 + j * 3 + 0] = src[(0 * HID + j) * HID + k];
        dst[k * 1536 + j * 3 + 1] = src[(1 * HID + j) * HID + k];
        dst[k * 1536 + j * 3 + 2] = src[(2 * HID + j) * HID + k];
    }
}

// ---- init: zero list counts + padded barrier flags ----
__global__ void init_ws(int* __restrict__ cnts, int* __restrict__ bars) {
    int i = blockIdx.x * blockDim.x + threadIdx.x;
    if (i < 3 * 2 * NB * 4) cnts[i] = 0;
    if (i < NB * 64) bars[i] = 0;
}

// kind: 0=dh0(A) 1=dx1(B) 2=dh1(C); slot: parity buffer; q: unit quarter
__device__ __forceinline__ int cidx(int kind, int slot, int b, int q) {
    return ((kind * 2 + slot) * NB + b) * 4 + q;
}
__device__ __forceinline__ int lofs(int kind, int slot, int b, int q) {
    return (((kind * 2 + slot) * NB + b) * 4 + q) * 128;   // uint2 units
}

// ---- coherent relaxed loads (no fences -> L2 weight lines stay resident) ----
__device__ __forceinline__ int ld_cnt(const int* p) {
    return __hip_atomic_load(p, __ATOMIC_RELAXED, __HIP_MEMORY_SCOPE_AGENT);
}
__device__ __forceinline__ uint2 ld_ent(const uint2* p) {
    unsigned long long r = __hip_atomic_load((const unsigned long long*)p,
                             __ATOMIC_RELAXED, __HIP_MEMORY_SCOPE_AGENT);
    return make_uint2((unsigned)r, (unsigned)(r >> 32));
}

// ---- depth-8 pipelined slot MAC, stride-8 entries ----
// Slot s processes entries 8j+s; only ONE slot (2 waves of 128 units) loads
// each entry -> 2 VMEM instrs/entry (dwordx3, all 3 gate weights).
// m = n/8 entries per slot, m multiple of 8 (n multiple of 64); pads (0,0)
// read row 0 with v=0 -> exact +0. e.x = pre-multiplied byte offset k*6144.
__device__ __forceinline__ void mac3s(const uint2* __restrict__ sl, int m,
                                      const char* __restrict__ cb,
                                      float& a0, float& a1, float& a2) {
    if (m <= 0) return;
    float  v0, v1, v2, v3, v4, v5, v6, v7;
    float3 w0, w1, w2, w3, w4, w5, w6, w7;
#define PISS(S, J) { uint2 e_ = sl[8 * (J)]; v##S = __uint_as_float(e_.y); \
    w##S = *(const float3*)(cb + e_.x); }
#define PCON(S, JN, MORE) { float3 W_ = w##S; float V_ = v##S; \
    if (MORE) PISS(S, (JN)) \
    a0 += V_ * W_.x; a1 += V_ * W_.y; a2 += V_ * W_.z; }
    PISS(0,0) PISS(1,1) PISS(2,2) PISS(3,3)
    PISS(4,4) PISS(5,5) PISS(6,6) PISS(7,7)
    #pragma unroll 1
    for (int j = 0; j < m; j += 8) {
        const int jn = j + 8;
        const bool more = jn < m;
        PCON(0,jn+0,more) PCON(1,jn+1,more) PCON(2,jn+2,more) PCON(3,jn+3,more)
        PCON(4,jn+4,more) PCON(5,jn+5,more) PCON(6,jn+6,more) PCON(7,jn+7,more)
    }
#undef PISS
#undef PCON
}

// ---- main kernel: 256 WGs = 64 batches x 4 unit-quarters (BOTH layers) ----
// Each WG: units [q*128,(q+1)*128) of L0 (step t) AND L1 (step t-1) -> all 4
// WGs of a batch do identical work (nA+nB+nC entries): no barrier imbalance.
// 1024 threads = 8 slots x 128 units; slot = tid>>7 (wave-uniform).
// XCD residency: (bq*4+q)%8 pins quarter-slices (2.25 MB) per XCD.
__global__ __launch_bounds__(1024, 4)
void dgru_q(const float* __restrict__ x,
            const float* __restrict__ wih0p,   // [6][512] float3
            const float* __restrict__ whh0p,   // [512][512] float3
            const float* __restrict__ wih1p,
            const float* __restrict__ whh1p,
            const float* __restrict__ bih0, const float* __restrict__ bhh0,
            const float* __restrict__ bih1, const float* __restrict__ bhh1,
            const float* __restrict__ wfc,
            uint2* __restrict__ lists, int* __restrict__ cnts,
            int* __restrict__ bars, float* __restrict__ ws_fc) {
    __shared__ float s_x[2 * NT];                  // 8 KB
    __shared__ float s_dx0[8];
    __shared__ float s_xp0[8];
    __shared__ uint2 s_lA[576], s_lB[576], s_lC[576];   // 13.5 KB
    __shared__ float s_pp[8][12][128];             // 48 KB slot partials
    __shared__ int   s_c1[2], s_c2[2], s_c3[2];
    __shared__ float s_fcp[2][2];

    const int wgid = blockIdx.x;
    const int bq   = wgid >> 2;
    const int q    = wgid & 3;
    const int tid  = threadIdx.x;
    const int lane = tid & 63;
    const int wave = tid >> 6;        // 0..15
    const int slot = tid >> 7;        // 0..7, wave-uniform
    const int u    = tid & 127;
    const int uu   = q * 128 + u;     // global unit id

    // carries + unit state for BOTH layers (tid<128 meaningful)
    float cr0 = 0.f, cz0 = 0.f, cn0 = 0.f, cnh0 = 0.f;
    float cr1 = 0.f, cz1 = 0.f, cn1 = 0.f, cnh1 = 0.f;
    float h0 = 0.f, h0p = 0.f, xp1 = 0.f, h1 = 0.f, h1p = 0.f;
    float wfc0 = 0.f, wfc1 = 0.f;
    if (tid < 128) {
        cr0  = bih0[uu]         + bhh0[uu];
        cz0  = bih0[HID + uu]   + bhh0[HID + uu];
        cn0  = bih0[2*HID + uu];
        cnh0 = bhh0[2*HID + uu];
        cr1  = bih1[uu]         + bhh1[uu];
        cz1  = bih1[HID + uu]   + bhh1[HID + uu];
        cn1  = bih1[2*HID + uu];
        cnh1 = bhh1[2*HID + uu];
        wfc0 = wfc[uu]; wfc1 = wfc[HID + uu];
    }

    // per-thread column bases (12 B per unit)
    const char* c_ih0 = (const char*)wih0p + uu * 12;
    const char* c_hh0 = (const char*)whh0p + uu * 12;
    const char* c_ih1 = (const char*)wih1p + uu * 12;
    const char* c_hh1 = (const char*)whh1p + uu * 12;

    for (int i = tid; i < 2 * NT; i += 1024) s_x[i] = x[bq * 2 * NT + i];
    if (tid < 8) { s_xp0[tid] = 0.f; s_dx0[tid] = 0.f; }
    __syncthreads();

    for (int t = 0; t <= NT; ++t) {
        const int rs = t & 1, ps = (t + 1) & 1;
        // ===== stage phase: all needed lists -> LDS (merged, k ascending) ==
        int cA[4], cB[4], cC[4];
        int nA = 0, nB = 0, nC = 0;
        if (t < NT) {
            #pragma unroll
            for (int qq = 0; qq < 4; ++qq) { cA[qq] = ld_cnt(&cnts[cidx(0, rs, bq, qq)]); nA += cA[qq]; }
        }
        if (t > 0) {
            #pragma unroll
            for (int qq = 0; qq < 4; ++qq) {
                cB[qq] = ld_cnt(&cnts[cidx(1, rs, bq, qq)]); nB += cB[qq];
                cC[qq] = ld_cnt(&cnts[cidx(2, rs, bq, qq)]); nC += cC[qq];
            }
        }
        const int nAp = (nA + 63) & ~63;
        const int nBp = (nB + 63) & ~63;
        const int nCp = (nC + 63) & ~63;
        if (t < NT) {
            for (int i = tid; i < nAp; i += 1024) {
                if (i < nA) {
                    int xx = i, qq = 0;
                    while (xx >= cA[qq]) { xx -= cA[qq]; ++qq; }
                    s_lA[i] = ld_ent(lists + lofs(0, rs, bq, qq) + xx);
                } else s_lA[i] = make_uint2(0u, 0u);
            }
            if (tid < 6) {                        // input features, step t
                float iv = s_x[2 * t], qv = s_x[2 * t + 1];
                float amp = sqrtf(iv * iv + qv * qv);
                float f;
                if      (tid == 0) f = iv;
                else if (tid == 1) f = qv;
                else if (tid == 2) f = amp;
                else if (tid == 3) f = amp * amp * amp;
                else if (tid == 4) f = qv / amp;
                else               f = iv / amp;
                float dx = f - s_xp0[tid];
                if (fabsf(dx) < THX) dx = 0.f; else s_xp0[tid] = f;
                s_dx0[tid] = dx;
            }
        }
        if (t > 0) {
            for (int i = tid; i < nBp; i += 1024) {
                if (i < nB) {
                    int xx = i, qq = 0;
                    while (xx >= cB[qq]) { xx -= cB[qq]; ++qq; }
                    s_lB[i] = ld_ent(lists + lofs(1, rs, bq, qq) + xx);
                } else s_lB[i] = make_uint2(0u, 0u);
            }
            for (int i = tid; i < nCp; i += 1024) {
                if (i < nC) {
                    int xx = i, qq = 0;
                    while (xx >= cC[qq]) { xx -= cC[qq]; ++qq; }
                    s_lC[i] = ld_ent(lists + lofs(2, rs, bq, qq) + xx);
                } else s_lC[i] = make_uint2(0u, 0u);
            }
        }
        __syncthreads();                                     // S1

        // ===== MAC phase: slot-parallel over both layers ==================
        if (t < NT) {
            float hR = 0.f, hZ = 0.f, hNH = 0.f;
            mac3s(s_lA + slot, nAp >> 3, c_hh0, hR, hZ, hNH);
            s_pp[slot][0][u] = hR;
            s_pp[slot][1][u] = hZ;
            s_pp[slot][2][u] = hNH;
            if (slot == 0) {                      // dense ih0 (6 features)
                float iR = 0.f, iZ = 0.f, iN = 0.f;
                #pragma unroll
                for (int f = 0; f < 6; ++f) {     // dv==0 adds exact +0
                    float dv = s_dx0[f];
                    float3 w = *(const float3*)(c_ih0 + f * 6144);
                    iR += dv * w.x; iZ += dv * w.y; iN += dv * w.z;
                }
                s_pp[0][3][u] = iR;
                s_pp[0][4][u] = iZ;
                s_pp[0][5][u] = iN;
            }
        }
        if (t > 0) {
            float iR = 0.f, iZ = 0.f, iN = 0.f;
            float hR = 0.f, hZ = 0.f, hNH = 0.f;
            mac3s(s_lB + slot, nBp >> 3, c_ih1, iR, iZ, iN);
            mac3s(s_lC + slot, nCp >> 3, c_hh1, hR, hZ, hNH);
            s_pp[slot][6][u]  = iR;
            s_pp[slot][7][u]  = iZ;
            s_pp[slot][8][u]  = iN;
            s_pp[slot][9][u]  = hR;
            s_pp[slot][10][u] = hZ;
            s_pp[slot][11][u] = hNH;
        }
        __syncthreads();                                     // S2

        // ===== unit phase (tid<128): merge, gates, deltas, FC =============
        float dA = 0.f, dB = 0.f, dC = 0.f;
        bool nzA = false, nzB = false, nzC = false;
        unsigned long long mA = 0, mB = 0, mC = 0;
        if (tid < 128) {
            if (t < NT) {
                float mhR = 0.f, mhZ = 0.f, mhN = 0.f;
                #pragma unroll
                for (int s = 0; s < 8; ++s) {
                    mhR += s_pp[s][0][u]; mhZ += s_pp[s][1][u]; mhN += s_pp[s][2][u];
                }
                float ar  = cr0 + s_pp[0][3][u] + mhR;   // carry + mac_x + mac_h
                float az  = cz0 + s_pp[0][4][u] + mhZ;
                float an  = cn0 + s_pp[0][5][u];
                float anh = cnh0 + mhN;
                cr0 = ar; cz0 = az; cn0 = an; cnh0 = anh;
                float r = 1.f / (1.f + expf(-ar));
                float z = 1.f / (1.f + expf(-az));
                float n = tanhf(an + r * anh);
                h0 = (1.f - z) * n + z * h0;
                dA = h0 - h0p; if (fabsf(dA) < THH) dA = 0.f; else h0p = h0;
                dB = h0 - xp1; if (fabsf(dB) < THX) dB = 0.f; else xp1 = h0;
                nzA = dA != 0.f; nzB = dB != 0.f;
            }
            if (t > 0) {
                float xiR = 0.f, xiZ = 0.f, xiN = 0.f;
                float mhR = 0.f, mhZ = 0.f, mhN = 0.f;
                #pragma unroll
                for (int s = 0; s < 8; ++s) {
                    xiR += s_pp[s][6][u];  xiZ += s_pp[s][7][u];  xiN += s_pp[s][8][u];
                    mhR += s_pp[s][9][u];  mhZ += s_pp[s][10][u]; mhN += s_pp[s][11][u];
                }
                float ar  = cr1 + xiR + mhR;
                float az  = cz1 + xiZ + mhZ;
                float an  = cn1 + xiN;
                float anh = cnh1 + mhN;
                cr1 = ar; cz1 = az; cn1 = an; cnh1 = anh;
                float r = 1.f / (1.f + expf(-ar));
                float z = 1.f / (1.f + expf(-az));
                float n = tanhf(an + r * anh);
                h1 = (1.f - z) * n + z * h1;
                float p0 = h1 * wfc0, p1 = h1 * wfc1;
                #pragma unroll
                for (int off = 32; off > 0; off >>= 1) {
                    p0 += __shfl_down(p0, off, 64);
                    p1 += __shfl_down(p1, off, 64);
                }
                if (lane == 0) { s_fcp[wave][0] = p0; s_fcp[wave][1] = p1; }
                if (t < NT) {
                    dC = h1 - h1p; if (fabsf(dC) < THH) dC = 0.f; else h1p = h1;
                    nzC = dC != 0.f;
                }
            }
            mA = __ballot(nzA); mB = __ballot(nzB); mC = __ballot(nzC);
            if (lane == 0) {
                s_c1[wave] = __popcll(mA);
                s_c2[wave] = __popcll(mB);
                s_c3[wave] = __popcll(mC);
            }
        }
        __syncthreads();                                     // S3

        // ===== publish phase ==============================================
        if (tid < 128) {
            unsigned long long below = (1ull << lane) - 1;
            if (t < NT) {
                int preA = (wave == 1) ? s_c1[0] : 0;
                int preB = (wave == 1) ? s_c2[0] : 0;
                int preC = (wave == 1) ? s_c3[0] : 0;
                uint2* outA = lists + lofs(0, ps, bq, q);
                uint2* outB = lists + lofs(1, ps, bq, q);
                uint2* outC = lists + lofs(2, ps, bq, q);
                if (nzA) outA[preA + __popcll(mA & below)] =
                    make_uint2((unsigned)(uu * 6144u), __float_as_uint(dA));
                if (nzB) outB[preB + __popcll(mB & below)] =
                    make_uint2((unsigned)(uu * 6144u), __float_as_uint(dB));
                if (nzC) outC[preC + __popcll(mC & below)] =
                    make_uint2((unsigned)(uu * 6144u), __float_as_uint(dC));
                if (tid == 0) {
                    cnts[cidx(0, ps, bq, q)] = s_c1[0] + s_c1[1];
                    cnts[cidx(1, ps, bq, q)] = s_c2[0] + s_c2[1];
                    cnts[cidx(2, ps, bq, q)] = s_c3[0] + s_c3[1];
                }
            }
            if (t > 0 && tid == 0) {
                float2* dst = (float2*)(ws_fc + (((size_t)bq * NT + (t - 1)) * 4 + q) * 2);
                *dst = make_float2(s_fcp[0][0] + s_fcp[1][0],
                                   s_fcp[0][1] + s_fcp[1][1]);
            }
        }

        // ===== quad barrier (padded flag, release add, relaxed poll) ======
        if (t < NT) {
            __syncthreads();   // drains this WG's global stores before arrival
            if (tid == 0) {
                __hip_atomic_fetch_add(&bars[bq * 64], 1, __ATOMIC_RELEASE,
                                       __HIP_MEMORY_SCOPE_AGENT);
                while (__hip_atomic_load(&bars[bq * 64], __ATOMIC_RELAXED,
                                         __HIP_MEMORY_SCOPE_AGENT) < 4 * (t + 1))
                    __builtin_amdgcn_s_sleep(8);
            }
            __syncthreads();
        }
    }
}

// ---- epilogue: deterministic FC reduction over 4 quarters (ascending) ----
__global__ void fc_reduce(const float* __restrict__ ws_fc,
                          const float* __restrict__ bfc,
                          float* __restrict__ out) {
    int idx = blockIdx.x * blockDim.x + threadIdx.x;   // (b*NT + t)
    if (idx < NB * NT) {
        const float2* p = (const float2*)(ws_fc + (size_t)idx * 8);
        out[idx * 2 + 0] = bfc[0] + p[0].x + p[1].x + p[2].x + p[3].x;
        out[idx * 2 + 1] = bfc[1] + p[0].y + p[1].y + p[2].y + p[3].y;
    }
}

// ---- safety-net fallback (ws too small): dense branchy loops, inline FC ----
__global__ __launch_bounds__(512)
void dgru_raw(const float* __restrict__ x,
              const float* __restrict__ wih0, const float* __restrict__ whh0,
              const float* __restrict__ wih1, const float* __restrict__ whh1,
              const float* __restrict__ bih0, const float* __restrict__ bhh0,
              const float* __restrict__ bih1, const float* __restrict__ bhh1,
              const float* __restrict__ wfc,  const float* __restrict__ bfc,
              float* __restrict__ out) {
    __shared__ float s_dx0[8];
    __shared__ float s_xp0[8];
    __shared__ float s_dh0[HID];
    __shared__ float s_dx1[HID];
    __shared__ float s_dh1[HID];
    __shared__ float s_part[16];

    const int j = threadIdx.x;
    const int b = blockIdx.x;
    float h0 = 0.f, h0p = 0.f, xp1 = 0.f, h1 = 0.f, h1p = 0.f;
    float cr0 = bih0[j] + bhh0[j];
    float cz0 = bih0[HID + j] + bhh0[HID + j];
    float cn0 = bih0[2*HID + j];
    float cnh0 = bhh0[2*HID + j];
    float cr1 = bih1[j] + bhh1[j];
    float cz1 = bih1[HID + j] + bhh1[HID + j];
    float cn1 = bih1[2*HID + j];
    float cnh1 = bhh1[2*HID + j];
    if (j < 8) { s_xp0[j] = 0.f; s_dx0[j] = 0.f; }
    const float wfc0 = wfc[j], wfc1 = wfc[HID + j];
    __syncthreads();

    for (int t = 0; t < NT; ++t) {
        float d = h0 - h0p;
        if (fabsf(d) < THH) d = 0.f; else h0p = h0;
        s_dh0[j] = d;
        if (j < 6) {
            float iv = x[(b * NT + t) * 2 + 0];
            float qv = x[(b * NT + t) * 2 + 1];
            float amp = sqrtf(iv * iv + qv * qv);
            float f;
            if      (j == 0) f = iv;
            else if (j == 1) f = qv;
            else if (j == 2) f = amp;
            else if (j == 3) f = amp * amp * amp;
            else if (j == 4) f = qv / amp;
            else             f = iv / amp;
            float dx = f - s_xp0[j];
            if (fabsf(dx) < THX) dx = 0.f; else s_xp0[j] = f;
            s_dx0[j] = dx;
        }
        __syncthreads();
        {
            float ar = cr0, az = cz0, an = cn0, anh = cnh0;
            #pragma unroll
            for (int f = 0; f < 6; ++f) {
                float dv = s_dx0[f];
                ar += dv * wih0[j * 6 + f];
                az += dv * wih0[(HID + j) * 6 + f];
                an += dv * wih0[(2*HID + j) * 6 + f];
            }
            for (int k = 0; k < HID; ++k) {
                float dv = s_dh0[k];
                if (dv != 0.f) {
                    ar  += dv * whh0[j * HID + k];
                    az  += dv * whh0[(HID + j) * HID + k];
                    anh += dv * whh0[(2*HID + j) * HID + k];
                }
            }
            cr0 = ar; cz0 = az; cn0 = an; cnh0 = anh;
            float r = 1.f / (1.f + expf(-ar));
            float z = 1.f / (1.f + expf(-az));
            float n = tanhf(an + r * anh);
            h0 = (1.f - z) * n + z * h0;
        }
        float dxv = h0 - xp1;
        if (fabsf(dxv) < THX) dxv = 0.f; else xp1 = h0;
        s_dx1[j] = dxv;
        float dhv = h1 - h1p;
        if (fabsf(dhv) < THH) dhv = 0.f; else h1p = h1;
        s_dh1[j] = dhv;
        __syncthreads();
        {
            float ar = cr1, az = cz1, an = cn1, anh = cnh1;
            for (int k = 0; k < HID; ++k) {
                float dv = s_dx1[k];
                if (dv != 0.f) {
                    ar += dv * wih1[j * HID + k];
                    az += dv * wih1[(HID + j) * HID + k];
                    an += dv * wih1[(2*HID + j) * HID + k];
                }
            }
            for (int k = 0; k < HID; ++k) {
                float dv = s_dh1[k];
                if (dv != 0.f) {
                    ar  += dv * whh1[j * HID + k];
                    az  += dv * whh1[(HID + j) * HID + k];
                    anh += dv * whh1[(2*HID + j) * HID + k];
                }
            }
            cr1 = ar; cz1 = az; cn1 = an; cnh1 = anh;
            float r = 1.f / (1.f + expf(-ar));
            float z = 1.f / (1.f + expf(-az));
            float n = tanhf(an + r * anh);
            h1 = (1.f - z) * n + z * h1;
        }
        float p0 = h1 * wfc0, p1 = h1 * wfc1;
        #pragma unroll
        for (int off = 32; off > 0; off >>= 1) {
            p0 += __shfl_down(p0, off, 64);
            p1 += __shfl_down(p1, off, 64);
        }
        if ((j & 63) == 0) { s_part[(j >> 6) * 2] = p0; s_part[(j >> 6) * 2 + 1] = p1; }
        __syncthreads();
        if (j == 0) {
            float o0 = bfc[0], o1 = bfc[1];
            #pragma unroll
            for (int w = 0; w < 8; ++w) { o0 += s_part[w * 2]; o1 += s_part[w * 2 + 1]; }
            out[(b * NT + t) * 2 + 0] = o0;
            out[(b * NT + t) * 2 + 1] = o1;
        }
    }
}

extern "C" void kernel_launch(void* const* d_in, const int* in_sizes, int n_in,
                              void* d_out, int out_size, void* d_ws, size_t ws_size,
                              hipStream_t stream) {
    const float* x    = (const float*)d_in[0];
    // d_in[1] = h_0 : reference zero-inits h, input unused
    const float* wih0 = (const float*)d_in[2];
    const float* whh0 = (const float*)d_in[3];
    const float* bih0 = (const float*)d_in[4];
    const float* bhh0 = (const float*)d_in[5];
    const float* wih1 = (const float*)d_in[6];
    const float* whh1 = (const float*)d_in[7];
    const float* bih1 = (const float*)d_in[8];
    const float* bhh1 = (const float*)d_in[9];
    const float* wfc  = (const float*)d_in[10];
    const float* bfc  = (const float*)d_in[11];
    float* out = (float*)d_out;

    const size_t MAT3    = (size_t)HID * 1536 * sizeof(float);     // 3 MiB each
    const size_t o_ih0   = 0;                                       // 36,864 B
    const size_t o_hh0   = 6 * 1536 * sizeof(float);
    const size_t o_ih1   = o_hh0 + MAT3;
    const size_t o_hh1   = o_ih1 + MAT3;
    const size_t o_lists = o_hh1 + MAT3;
    const size_t LISTS_B = (size_t)3 * 2 * NB * 4 * 128 * 8;        // 1.5 MiB
    const size_t o_cnts  = o_lists + LISTS_B;
    const size_t o_bars  = o_cnts + (size_t)3 * 2 * NB * 4 * sizeof(int);
    const size_t o_fc    = o_bars + (size_t)NB * 64 * sizeof(int);
    const size_t FCB     = (size_t)NB * NT * 4 * 2 * sizeof(float); // 2 MiB
    const size_t need    = o_fc + FCB;                              // ~13 MiB

    if (ws_size >= need) {
        float* wt_ih0 = (float*)((char*)d_ws + o_ih0);
        float* wt_hh0 = (float*)((char*)d_ws + o_hh0);
        float* wt_ih1 = (float*)((char*)d_ws + o_ih1);
        float* wt_hh1 = (float*)((char*)d_ws + o_hh1);
        uint2* g_lists = (uint2*)((char*)d_ws + o_lists);
        int*   g_cnts  = (int*)((char*)d_ws + o_cnts);
        int*   g_bars  = (int*)((char*)d_ws + o_bars);
        float* g_fc    = (float*)((char*)d_ws + o_fc);

        pack_ih0<<<(6 * HID + 255) / 256, 256, 0, stream>>>(wih0, wt_ih0);
        pack_h3<<<(HID * HID + 255) / 256, 256, 0, stream>>>(whh0, wt_hh0);
        pack_h3<<<(HID * HID + 255) / 256, 256, 0, stream>>>(wih1, wt_ih1);
        pack_h3<<<(HID * HID + 255) / 256, 256, 0, stream>>>(whh1, wt_hh1);
        init_ws<<<4, 1024, 0, stream>>>(g_cnts, g_bars);
        dgru_q<<<4 * NB, 1024, 0, stream>>>(x, wt_ih0, wt_hh0, wt_ih1, wt_hh1,
                                            bih0, bhh0, bih1, bhh1, wfc,
                                            g_lists, g_cnts, g_bars, g_fc);
        fc_reduce<<<(NB * NT + 255) / 256, 256, 0, stream>>>(g_fc, bfc, out);
    } else {
        dgru_raw<<<NB, HID, 0, stream>>>(x, wih0, whh0, wih1, whh1,
                                         bih0, bhh0, bih1, bhh1, wfc, bfc, out);
    }
}

// Round 16
// 30124.371 us; speedup vs baseline: 2.5809x; 1.0191x over previous
//
#include <hip/hip_runtime.h>

#define HID 512
#define NB  64
#define NT  1024
#define THX 0.1f
#define THH 0.05f

// ---- prep: pack W_ih_l0 [1536][6] f32 -> [6][512]{r,z,n} float3 ----
__global__ void pack_ih0(const float* __restrict__ src, float* __restrict__ dst) {
    int idx = blockIdx.x * blockDim.x + threadIdx.x;
    if (idx < 6 * HID) {
        int f = idx / HID, j = idx % HID;
        dst[f * 1536 + j * 3 + 0] = src[(0 * HID + j) * 6 + f];
        dst[f * 1536 + j * 3 + 1] = src[(1 * HID + j) * 6 + f];
        dst[f * 1536 + j * 3 + 2] = src[(2 * HID + j) * 6 + f];
    }
}

// ---- prep: pack a [1536][512] f32 matrix -> [512(k)][512(j)]{r,z,n} float3 ----
__global__ void pack_h3(const float* __restrict__ src, float* __restrict__ dst) {
    int idx = blockIdx.x * blockDim.x + threadIdx.x;
    if (idx < HID * HID) {
        int k = idx / HID, j = idx % HID;
        dst[k * 1536 + j * 3 + 0] = src[(0 * HID + j) * HID + k];
        dst[k * 1536 + j * 3 + 1] = src[(1 * HID + j) * HID + k];
        dst[k * 1536 + j * 3 + 2] = src[(2 * HID + j) * HID + k];
    }
}

// ---- init: zero packed count words (tag 0 == expected at t=0) ----
__global__ void init_ws(int* __restrict__ cnts) {
    int i = blockIdx.x * blockDim.x + threadIdx.x;
    if (i < 4 * NB * 4) cnts[i] = 0;
}

// packed count word index: (slot4, batch, quarter)
__device__ __forceinline__ int widx(int slot, int b, int q) {
    return (slot * NB + b) * 4 + q;
}
// list region: kind {0=A dh0, 1=B dx1, 2=C dh1}, 4-deep slot, batch, quarter
__device__ __forceinline__ int lofs(int kind, int slot, int b, int q) {
    return (((kind * 4 + slot) * NB + b) * 4 + q) * 128;   // uint2 units
}

// ---- coherent relaxed ops (LLC point; no fences -> weight L2 lines live) ----
__device__ __forceinline__ int ld_cnt(const int* p) {
    return __hip_atomic_load(p, __ATOMIC_RELAXED, __HIP_MEMORY_SCOPE_AGENT);
}
__device__ __forceinline__ uint2 ld_ent(const uint2* p) {
    unsigned long long r = __hip_atomic_load((const unsigned long long*)p,
                             __ATOMIC_RELAXED, __HIP_MEMORY_SCOPE_AGENT);
    return make_uint2((unsigned)r, (unsigned)(r >> 32));
}

// ---- depth-8 pipelined slot MAC, stride-8 entries (r15, unchanged) ----
__device__ __forceinline__ void mac3s(const uint2* __restrict__ sl, int m,
                                      const char* __restrict__ cb,
                                      float& a0, float& a1, float& a2) {
    if (m <= 0) return;
    float  v0, v1, v2, v3, v4, v5, v6, v7;
    float3 w0, w1, w2, w3, w4, w5, w6, w7;
#define PISS(S, J) { uint2 e_ = sl[8 * (J)]; v##S = __uint_as_float(e_.y); \
    w##S = *(const float3*)(cb + e_.x); }
#define PCON(S, JN, MORE) { float3 W_ = w##S; float V_ = v##S; \
    if (MORE) PISS(S, (JN)) \
    a0 += V_ * W_.x; a1 += V_ * W_.y; a2 += V_ * W_.z; }
    PISS(0,0) PISS(1,1) PISS(2,2) PISS(3,3)
    PISS(4,4) PISS(5,5) PISS(6,6) PISS(7,7)
    #pragma unroll 1
    for (int j = 0; j < m; j += 8) {
        const int jn = j + 8;
        const bool more = jn < m;
        PCON(0,jn+0,more) PCON(1,jn+1,more) PCON(2,jn+2,more) PCON(3,jn+3,more)
        PCON(4,jn+4,more) PCON(5,jn+5,more) PCON(6,jn+6,more) PCON(7,jn+7,more)
    }
#undef PISS
#undef PCON
}

// ---- main kernel: 256 WGs = 64 batches x 4 unit-quarters (both layers) ----
// r15 compute, with LOCK-FREE TAG-POLLING sync replacing the central barrier:
//  * each WG publishes ONE packed word (tag8|cC|cB|cA) per step via a release
//    store (release = L2 writeback of its freshly written list entries);
//  * 4 lanes poll the 4 quarter words until tag==t, broadcast via LDS
//    (counts read ONCE per WG vs 12x1024 LLC atomic loads in r15);
//  * lists are 4-deep rotated: writer of slot s at step s+4 has observed
//    tags s+2 from all quarters => all readers of slot s (step s+1) done.
//    Skew bound 3 < 4 => race-free; mod-256 tag unambiguous at skew 3.
__global__ __launch_bounds__(1024, 4)
void dgru_q(const float* __restrict__ x,
            const float* __restrict__ wih0p,   // [6][512] float3
            const float* __restrict__ whh0p,   // [512][512] float3
            const float* __restrict__ wih1p,
            const float* __restrict__ whh1p,
            const float* __restrict__ bih0, const float* __restrict__ bhh0,
            const float* __restrict__ bih1, const float* __restrict__ bhh1,
            const float* __restrict__ wfc,
            uint2* __restrict__ lists, int* __restrict__ cnts,
            float* __restrict__ ws_fc) {
    __shared__ float s_x[2 * NT];                  // 8 KB
    __shared__ float s_dx0[8];
    __shared__ float s_xp0[8];
    __shared__ unsigned s_cw[4];
    __shared__ uint2 s_lA[576], s_lB[576], s_lC[576];   // 13.5 KB
    __shared__ float s_pp[8][12][128];             // 48 KB slot partials
    __shared__ int   s_c1[2], s_c2[2], s_c3[2];
    __shared__ float s_fcp[2][2];

    const int wgid = blockIdx.x;
    const int bq   = wgid >> 2;
    const int q    = wgid & 3;
    const int tid  = threadIdx.x;
    const int lane = tid & 63;
    const int wave = tid >> 6;        // 0..15
    const int slot = tid >> 7;        // 0..7, wave-uniform
    const int u    = tid & 127;
    const int uu   = q * 128 + u;     // global unit id

    // carries + unit state for BOTH layers (tid<128 meaningful)
    float cr0 = 0.f, cz0 = 0.f, cn0 = 0.f, cnh0 = 0.f;
    float cr1 = 0.f, cz1 = 0.f, cn1 = 0.f, cnh1 = 0.f;
    float h0 = 0.f, h0p = 0.f, xp1 = 0.f, h1 = 0.f, h1p = 0.f;
    float wfc0 = 0.f, wfc1 = 0.f;
    if (tid < 128) {
        cr0  = bih0[uu]         + bhh0[uu];
        cz0  = bih0[HID + uu]   + bhh0[HID + uu];
        cn0  = bih0[2*HID + uu];
        cnh0 = bhh0[2*HID + uu];
        cr1  = bih1[uu]         + bhh1[uu];
        cz1  = bih1[HID + uu]   + bhh1[HID + uu];
        cn1  = bih1[2*HID + uu];
        cnh1 = bhh1[2*HID + uu];
        wfc0 = wfc[uu]; wfc1 = wfc[HID + uu];
    }

    // per-thread column bases (12 B per unit)
    const char* c_ih0 = (const char*)wih0p + uu * 12;
    const char* c_hh0 = (const char*)whh0p + uu * 12;
    const char* c_ih1 = (const char*)wih1p + uu * 12;
    const char* c_hh1 = (const char*)whh1p + uu * 12;

    for (int i = tid; i < 2 * NT; i += 1024) s_x[i] = x[bq * 2 * NT + i];
    if (tid < 8) { s_xp0[tid] = 0.f; s_dx0[tid] = 0.f; }
    __syncthreads();

    for (int t = 0; t <= NT; ++t) {
        const int slot_r = (t + 3) & 3;    // (t-1) mod 4: data published at t-1
        const int slot_w = t & 3;
        // ===== S0: poll the 4 quarter count-words (4 lanes), broadcast =====
        if (tid < 4) {
            const unsigned expct = (unsigned)(t & 0xFF);
            const int* wp = &cnts[widx(slot_r, bq, tid)];
            unsigned v;
            while (((v = (unsigned)ld_cnt(wp)) >> 24) != expct)
                __builtin_amdgcn_s_sleep(4);
            s_cw[tid] = v;
        }
        __syncthreads();                                     // S0
        int cA[4], cB[4], cC[4];
        int nA = 0, nB = 0, nC = 0;
        #pragma unroll
        for (int qq = 0; qq < 4; ++qq) {
            unsigned v = s_cw[qq];
            cA[qq] = (int)(v & 0xFF);
            cB[qq] = (int)((v >> 8) & 0xFF);
            cC[qq] = (int)((v >> 16) & 0xFF);
            nA += cA[qq]; nB += cB[qq]; nC += cC[qq];
        }
        const int nAp = (nA + 63) & ~63;
        const int nBp = (nB + 63) & ~63;
        const int nCp = (nC + 63) & ~63;

        // ===== stage phase: needed lists -> LDS (merged, k ascending) =====
        if (t < NT) {
            for (int i = tid; i < nAp; i += 1024) {
                if (i < nA) {
                    int xx = i, qq = 0;
                    while (xx >= cA[qq]) { xx -= cA[qq]; ++qq; }
                    s_lA[i] = ld_ent(lists + lofs(0, slot_r, bq, qq) + xx);
                } else s_lA[i] = make_uint2(0u, 0u);
            }
            if (tid < 6) {                        // input features, step t
                float iv = s_x[2 * t], qv = s_x[2 * t + 1];
                float amp = sqrtf(iv * iv + qv * qv);
                float f;
                if      (tid == 0) f = iv;
                else if (tid == 1) f = qv;
                else if (tid == 2) f = amp;
                else if (tid == 3) f = amp * amp * amp;
                else if (tid == 4) f = qv / amp;
                else               f = iv / amp;
                float dx = f - s_xp0[tid];
                if (fabsf(dx) < THX) dx = 0.f; else s_xp0[tid] = f;
                s_dx0[tid] = dx;
            }
        }
        if (t > 0) {
            for (int i = tid; i < nBp; i += 1024) {
                if (i < nB) {
                    int xx = i, qq = 0;
                    while (xx >= cB[qq]) { xx -= cB[qq]; ++qq; }
                    s_lB[i] = ld_ent(lists + lofs(1, slot_r, bq, qq) + xx);
                } else s_lB[i] = make_uint2(0u, 0u);
            }
            for (int i = tid; i < nCp; i += 1024) {
                if (i < nC) {
                    int xx = i, qq = 0;
                    while (xx >= cC[qq]) { xx -= cC[qq]; ++qq; }
                    s_lC[i] = ld_ent(lists + lofs(2, slot_r, bq, qq) + xx);
                } else s_lC[i] = make_uint2(0u, 0u);
            }
        }
        __syncthreads();                                     // S1

        // ===== MAC phase: slot-parallel over both layers ==================
        if (t < NT) {
            float hR = 0.f, hZ = 0.f, hNH = 0.f;
            mac3s(s_lA + slot, nAp >> 3, c_hh0, hR, hZ, hNH);
            s_pp[slot][0][u] = hR;
            s_pp[slot][1][u] = hZ;
            s_pp[slot][2][u] = hNH;
            if (slot == 0) {                      // dense ih0 (6 features)
                float iR = 0.f, iZ = 0.f, iN = 0.f;
                #pragma unroll
                for (int f = 0; f < 6; ++f) {     // dv==0 adds exact +0
                    float dv = s_dx0[f];
                    float3 w = *(const float3*)(c_ih0 + f * 6144);
                    iR += dv * w.x; iZ += dv * w.y; iN += dv * w.z;
                }
                s_pp[0][3][u] = iR;
                s_pp[0][4][u] = iZ;
                s_pp[0][5][u] = iN;
            }
        }
        if (t > 0) {
            float iR = 0.f, iZ = 0.f, iN = 0.f;
            float hR = 0.f, hZ = 0.f, hNH = 0.f;
            mac3s(s_lB + slot, nBp >> 3, c_ih1, iR, iZ, iN);
            mac3s(s_lC + slot, nCp >> 3, c_hh1, hR, hZ, hNH);
            s_pp[slot][6][u]  = iR;
            s_pp[slot][7][u]  = iZ;
            s_pp[slot][8][u]  = iN;
            s_pp[slot][9][u]  = hR;
            s_pp[slot][10][u] = hZ;
            s_pp[slot][11][u] = hNH;
        }
        __syncthreads();                                     // S2

        // ===== unit phase (tid<128): merge, gates, deltas, FC =============
        float dA = 0.f, dB = 0.f, dC = 0.f;
        bool nzA = false, nzB = false, nzC = false;
        unsigned long long mA = 0, mB = 0, mC = 0;
        if (tid < 128) {
            if (t < NT) {
                float mhR = 0.f, mhZ = 0.f, mhN = 0.f;
                #pragma unroll
                for (int s = 0; s < 8; ++s) {
                    mhR += s_pp[s][0][u]; mhZ += s_pp[s][1][u]; mhN += s_pp[s][2][u];
                }
                float ar  = cr0 + s_pp[0][3][u] + mhR;   // carry + mac_x + mac_h
                float az  = cz0 + s_pp[0][4][u] + mhZ;
                float an  = cn0 + s_pp[0][5][u];
                float anh = cnh0 + mhN;
                cr0 = ar; cz0 = az; cn0 = an; cnh0 = anh;
                float r = 1.f / (1.f + expf(-ar));
                float z = 1.f / (1.f + expf(-az));
                float n = tanhf(an + r * anh);
                h0 = (1.f - z) * n + z * h0;
                dA = h0 - h0p; if (fabsf(dA) < THH) dA = 0.f; else h0p = h0;
                dB = h0 - xp1; if (fabsf(dB) < THX) dB = 0.f; else xp1 = h0;
                nzA = dA != 0.f; nzB = dB != 0.f;
            }
            if (t > 0) {
                float xiR = 0.f, xiZ = 0.f, xiN = 0.f;
                float mhR = 0.f, mhZ = 0.f, mhN = 0.f;
                #pragma unroll
                for (int s = 0; s < 8; ++s) {
                    xiR += s_pp[s][6][u];  xiZ += s_pp[s][7][u];  xiN += s_pp[s][8][u];
                    mhR += s_pp[s][9][u];  mhZ += s_pp[s][10][u]; mhN += s_pp[s][11][u];
                }
                float ar  = cr1 + xiR + mhR;
                float az  = cz1 + xiZ + mhZ;
                float an  = cn1 + xiN;
                float anh = cnh1 + mhN;
                cr1 = ar; cz1 = az; cn1 = an; cnh1 = anh;
                float r = 1.f / (1.f + expf(-ar));
                float z = 1.f / (1.f + expf(-az));
                float n = tanhf(an + r * anh);
                h1 = (1.f - z) * n + z * h1;
                float p0 = h1 * wfc0, p1 = h1 * wfc1;
                #pragma unroll
                for (int off = 32; off > 0; off >>= 1) {
                    p0 += __shfl_down(p0, off, 64);
                    p1 += __shfl_down(p1, off, 64);
                }
                if (lane == 0) { s_fcp[wave][0] = p0; s_fcp[wave][1] = p1; }
                if (t < NT) {
                    dC = h1 - h1p; if (fabsf(dC) < THH) dC = 0.f; else h1p = h1;
                    nzC = dC != 0.f;
                }
            }
            mA = __ballot(nzA); mB = __ballot(nzB); mC = __ballot(nzC);
            if (lane == 0) {
                s_c1[wave] = __popcll(mA);
                s_c2[wave] = __popcll(mB);
                s_c3[wave] = __popcll(mC);
            }
        }
        __syncthreads();                                     // S3

        // ===== publish phase (entries; plain stores, flushed by release) ===
        if (tid < 128 && t < NT) {
            unsigned long long below = (1ull << lane) - 1;
            int preA = (wave == 1) ? s_c1[0] : 0;
            int preB = (wave == 1) ? s_c2[0] : 0;
            int preC = (wave == 1) ? s_c3[0] : 0;
            uint2* outA = lists + lofs(0, slot_w, bq, q);
            uint2* outB = lists + lofs(1, slot_w, bq, q);
            uint2* outC = lists + lofs(2, slot_w, bq, q);
            if (nzA) outA[preA + __popcll(mA & below)] =
                make_uint2((unsigned)(uu * 6144u), __float_as_uint(dA));
            if (nzB) outB[preB + __popcll(mB & below)] =
                make_uint2((unsigned)(uu * 6144u), __float_as_uint(dB));
            if (nzC) outC[preC + __popcll(mC & below)] =
                make_uint2((unsigned)(uu * 6144u), __float_as_uint(dC));
        }
        if (t > 0 && tid == 0) {
            float2* dst = (float2*)(ws_fc + (((size_t)bq * NT + (t - 1)) * 4 + q) * 2);
            *dst = make_float2(s_fcp[0][0] + s_fcp[1][0],
                               s_fcp[0][1] + s_fcp[1][1]);
        }
        __syncthreads();                                     // S4 (drain stores)

        // ===== release-publish the packed count word ======================
        if (t < NT && tid == 0) {
            unsigned word = ((unsigned)((t + 1) & 0xFF) << 24)
                          | ((unsigned)(s_c3[0] + s_c3[1]) << 16)
                          | ((unsigned)(s_c2[0] + s_c2[1]) << 8)
                          |  (unsigned)(s_c1[0] + s_c1[1]);
            __hip_atomic_store(&cnts[widx(slot_w, bq, q)], (int)word,
                               __ATOMIC_RELEASE, __HIP_MEMORY_SCOPE_AGENT);
        }
    }
}

// ---- epilogue: deterministic FC reduction over 4 quarters (ascending) ----
__global__ void fc_reduce(const float* __restrict__ ws_fc,
                          const float* __restrict__ bfc,
                          float* __restrict__ out) {
    int idx = blockIdx.x * blockDim.x + threadIdx.x;   // (b*NT + t)
    if (idx < NB * NT) {
        const float2* p = (const float2*)(ws_fc + (size_t)idx * 8);
        out[idx * 2 + 0] = bfc[0] + p[0].x + p[1].x + p[2].x + p[3].x;
        out[idx * 2 + 1] = bfc[1] + p[0].y + p[1].y + p[2].y + p[3].y;
    }
}

// ---- safety-net fallback (ws too small): dense branchy loops, inline FC ----
__global__ __launch_bounds__(512)
void dgru_raw(const float* __restrict__ x,
              const float* __restrict__ wih0, const float* __restrict__ whh0,
              const float* __restrict__ wih1, const float* __restrict__ whh1,
              const float* __restrict__ bih0, const float* __restrict__ bhh0,
              const float* __restrict__ bih1, const float* __restrict__ bhh1,
              const float* __restrict__ wfc,  const float* __restrict__ bfc,
              float* __restrict__ out) {
    __shared__ float s_dx0[8];
    __shared__ float s_xp0[8];
    __shared__ float s_dh0[HID];
    __shared__ float s_dx1[HID];
    __shared__ float s_dh1[HID];
    __shared__ float s_part[16];

    const int j = threadIdx.x;
    const int b = blockIdx.x;
    float h0 = 0.f, h0p = 0.f, xp1 = 0.f, h1 = 0.f, h1p = 0.f;
    float cr0 = bih0[j] + bhh0[j];
    float cz0 = bih0[HID + j] + bhh0[HID + j];
    float cn0 = bih0[2*HID + j];
    float cnh0 = bhh0[2*HID + j];
    float cr1 = bih1[j] + bhh1[j];
    float cz1 = bih1[HID + j] + bhh1[HID + j];
    float cn1 = bih1[2*HID + j];
    float cnh1 = bhh1[2*HID + j];
    if (j < 8) { s_xp0[j] = 0.f; s_dx0[j] = 0.f; }
    const float wfc0 = wfc[j], wfc1 = wfc[HID + j];
    __syncthreads();

    for (int t = 0; t < NT; ++t) {
        float d = h0 - h0p;
        if (fabsf(d) < THH) d = 0.f; else h0p = h0;
        s_dh0[j] = d;
        if (j < 6) {
            float iv = x[(b * NT + t) * 2 + 0];
            float qv = x[(b * NT + t) * 2 + 1];
            float amp = sqrtf(iv * iv + qv * qv);
            float f;
            if      (j == 0) f = iv;
            else if (j == 1) f = qv;
            else if (j == 2) f = amp;
            else if (j == 3) f = amp * amp * amp;
            else if (j == 4) f = qv / amp;
            else             f = iv / amp;
            float dx = f - s_xp0[j];
            if (fabsf(dx) < THX) dx = 0.f; else s_xp0[j] = f;
            s_dx0[j] = dx;
        }
        __syncthreads();
        {
            float ar = cr0, az = cz0, an = cn0, anh = cnh0;
            #pragma unroll
            for (int f = 0; f < 6; ++f) {
                float dv = s_dx0[f];
                ar += dv * wih0[j * 6 + f];
                az += dv * wih0[(HID + j) * 6 + f];
                an += dv * wih0[(2*HID + j) * 6 + f];
            }
            for (int k = 0; k < HID; ++k) {
                float dv = s_dh0[k];
                if (dv != 0.f) {
                    ar  += dv * whh0[j * HID + k];
                    az  += dv * whh0[(HID + j) * HID + k];
                    anh += dv * whh0[(2*HID + j) * HID + k];
                }
            }
            cr0 = ar; cz0 = az; cn0 = an; cnh0 = anh;
            float r = 1.f / (1.f + expf(-ar));
            float z = 1.f / (1.f + expf(-az));
            float n = tanhf(an + r * anh);
            h0 = (1.f - z) * n + z * h0;
        }
        float dxv = h0 - xp1;
        if (fabsf(dxv) < THX) dxv = 0.f; else xp1 = h0;
        s_dx1[j] = dxv;
        float dhv = h1 - h1p;
        if (fabsf(dhv) < THH) dhv = 0.f; else h1p = h1;
        s_dh1[j] = dhv;
        __syncthreads();
        {
            float ar = cr1, az = cz1, an = cn1, anh = cnh1;
            for (int k = 0; k < HID; ++k) {
                float dv = s_dx1[k];
                if (dv != 0.f) {
                    ar += dv * wih1[j * HID + k];
                    az += dv * wih1[(HID + j) * HID + k];
                    an += dv * wih1[(2*HID + j) * HID + k];
                }
            }
            for (int k = 0; k < HID; ++k) {
                float dv = s_dh1[k];
                if (dv != 0.f) {
                    ar  += dv * whh1[j * HID + k];
                    az  += dv * whh1[(HID + j) * HID + k];
                    anh += dv * whh1[(2*HID + j) * HID + k];
                }
            }
            cr1 = ar; cz1 = az; cn1 = an; cnh1 = anh;
            float r = 1.f / (1.f + expf(-ar));
            float z = 1.f / (1.f + expf(-az));
            float n = tanhf(an + r * anh);
            h1 = (1.f - z) * n + z * h1;
        }
        float p0 = h1 * wfc0, p1 = h1 * wfc1;
        #pragma unroll
        for (int off = 32; off > 0; off >>= 1) {
            p0 += __shfl_down(p0, off, 64);
            p1 += __shfl_down(p1, off, 64);
        }
        if ((j & 63) == 0) { s_part[(j >> 6) * 2] = p0; s_part[(j >> 6) * 2 + 1] = p1; }
        __syncthreads();
        if (j == 0) {
            float o0 = bfc[0], o1 = bfc[1];
            #pragma unroll
            for (int w = 0; w < 8; ++w) { o0 += s_part[w * 2]; o1 += s_part[w * 2 + 1]; }
            out[(b * NT + t) * 2 + 0] = o0;
            out[(b * NT + t) * 2 + 1] = o1;
        }
    }
}

extern "C" void kernel_launch(void* const* d_in, const int* in_sizes, int n_in,
                              void* d_out, int out_size, void* d_ws, size_t ws_size,
                              hipStream_t stream) {
    const float* x    = (const float*)d_in[0];
    // d_in[1] = h_0 : reference zero-inits h, input unused
    const float* wih0 = (const float*)d_in[2];
    const float* whh0 = (const float*)d_in[3];
    const float* bih0 = (const float*)d_in[4];
    const float* bhh0 = (const float*)d_in[5];
    const float* wih1 = (const float*)d_in[6];
    const float* whh1 = (const float*)d_in[7];
    const float* bih1 = (const float*)d_in[8];
    const float* bhh1 = (const float*)d_in[9];
    const float* wfc  = (const float*)d_in[10];
    const float* bfc  = (const float*)d_in[11];
    float* out = (float*)d_out;

    const size_t MAT3    = (size_t)HID * 1536 * sizeof(float);     // 3 MiB each
    const size_t o_ih0   = 0;                                       // 36,864 B
    const size_t o_hh0   = 6 * 1536 * sizeof(float);
    const size_t o_ih1   = o_hh0 + MAT3;
    const size_t o_hh1   = o_ih1 + MAT3;
    const size_t o_lists = o_hh1 + MAT3;
    const size_t LISTS_B = (size_t)3 * 4 * NB * 4 * 128 * 8;        // 3 MiB (4-deep)
    const size_t o_cnts  = o_lists + LISTS_B;
    const size_t o_fc    = o_cnts + (size_t)4 * NB * 4 * sizeof(int);
    const size_t FCB     = (size_t)NB * NT * 4 * 2 * sizeof(float); // 2 MiB
    const size_t need    = o_fc + FCB;                              // ~14.2 MiB

    if (ws_size >= need) {
        float* wt_ih0 = (float*)((char*)d_ws + o_ih0);
        float* wt_hh0 = (float*)((char*)d_ws + o_hh0);
        float* wt_ih1 = (float*)((char*)d_ws + o_ih1);
        float* wt_hh1 = (float*)((char*)d_ws + o_hh1);
        uint2* g_lists = (uint2*)((char*)d_ws + o_lists);
        int*   g_cnts  = (int*)((char*)d_ws + o_cnts);
        float* g_fc    = (float*)((char*)d_ws + o_fc);

        pack_ih0<<<(6 * HID + 255) / 256, 256, 0, stream>>>(wih0, wt_ih0);
        pack_h3<<<(HID * HID + 255) / 256, 256, 0, stream>>>(whh0, wt_hh0);
        pack_h3<<<(HID * HID + 255) / 256, 256, 0, stream>>>(wih1, wt_ih1);
        pack_h3<<<(HID * HID + 255) / 256, 256, 0, stream>>>(whh1, wt_hh1);
        init_ws<<<1, 1024, 0, stream>>>(g_cnts);
        dgru_q<<<4 * NB, 1024, 0, stream>>>(x, wt_ih0, wt_hh0, wt_ih1, wt_hh1,
                                            bih0, bhh0, bih1, bhh1, wfc,
                                            g_lists, g_cnts, g_fc);
        fc_reduce<<<(NB * NT + 255) / 256, 256, 0, stream>>>(g_fc, bfc, out);
    } else {
        dgru_raw<<<NB, HID, 0, stream>>>(x, wih0, whh0, wih1, whh1,
                                         bih0, bhh0, bih1, bhh1, wfc, bfc, out);
    }
}

// Round 17
// 23523.869 us; speedup vs baseline: 3.3050x; 1.2806x over previous
//
#include <hip/hip_runtime.h>

#define HID 512
#define NB  64
#define NT  1024
#define THX 0.1f
#define THH 0.05f

// ---- prep: pack W_ih_l0 [1536][6] f32 -> [6][512]{r,z,n} float3 ----
__global__ void pack_ih0(const float* __restrict__ src, float* __restrict__ dst) {
    int idx = blockIdx.x * blockDim.x + threadIdx.x;
    if (idx < 6 * HID) {
        int f = idx / HID, j = idx % HID;
        dst[f * 1536 + j * 3 + 0] = src[(0 * HID + j) * 6 + f];
        dst[f * 1536 + j * 3 + 1] = src[(1 * HID + j) * 6 + f];
        dst[f * 1536 + j * 3 + 2] = src[(2 * HID + j) * 6 + f];
    }
}

// ---- prep: pack a [1536][512] f32 matrix -> [512(k)][512(j)]{r,z,n} float3 ----
__global__ void pack_h3(const float* __restrict__ src, float* __restrict__ dst) {
    int idx = blockIdx.x * blockDim.x + threadIdx.x;
    if (idx < HID * HID) {
        int k = idx / HID, j = idx % HID;
        dst[k * 1536 + j * 3 + 0] = src[(0 * HID + j) * HID + k];
        dst[k * 1536 + j * 3 + 1] = src[(1 * HID + j) * HID + k];
        dst[k * 1536 + j * 3 + 2] = src[(2 * HID + j) * HID + k];
    }
}

// ---- init: zero packed count words (tag 0 == expected at t=0) ----
__global__ void init_ws(int* __restrict__ cnts) {
    int i = blockIdx.x * blockDim.x + threadIdx.x;
    if (i < 4 * NB * 4) cnts[i] = 0;
}

// packed count word index: (slot4, batch, quarter)
__device__ __forceinline__ int widx(int slot, int b, int q) {
    return (slot * NB + b) * 4 + q;
}
// list region: kind {0=A dh0, 1=B dx1, 2=C dh1}, 4-deep slot, batch, quarter
__device__ __forceinline__ int lofs(int kind, int slot, int b, int q) {
    return (((kind * 4 + slot) * NB + b) * 4 + q) * 128;   // uint2 units
}

// ---- coherent RELAXED ops only (LLC point; NO release anywhere in the hot
// loop -> no per-step L2 writeback sweeps; r10-r16 carried one release per
// WG per step, each compiling to an L2 flush = the suspected ~20us/step) ----
__device__ __forceinline__ int ld_cnt(const int* p) {
    return __hip_atomic_load(p, __ATOMIC_RELAXED, __HIP_MEMORY_SCOPE_AGENT);
}
__device__ __forceinline__ uint2 ld_ent(const uint2* p) {
    unsigned long long r = __hip_atomic_load((const unsigned long long*)p,
                             __ATOMIC_RELAXED, __HIP_MEMORY_SCOPE_AGENT);
    return make_uint2((unsigned)r, (unsigned)(r >> 32));
}
__device__ __forceinline__ void st_ent(uint2* p, unsigned a, unsigned b) {
    unsigned long long r = (unsigned long long)a | ((unsigned long long)b << 32);
    __hip_atomic_store((unsigned long long*)p, r,
                       __ATOMIC_RELAXED, __HIP_MEMORY_SCOPE_AGENT);
}
__device__ __forceinline__ void st_cnt(int* p, int v) {
    __hip_atomic_store(p, v, __ATOMIC_RELAXED, __HIP_MEMORY_SCOPE_AGENT);
}

// ---- depth-8 pipelined slot MAC, stride-8 entries (r15/r16, unchanged) ----
__device__ __forceinline__ void mac3s(const uint2* __restrict__ sl, int m,
                                      const char* __restrict__ cb,
                                      float& a0, float& a1, float& a2) {
    if (m <= 0) return;
    float  v0, v1, v2, v3, v4, v5, v6, v7;
    float3 w0, w1, w2, w3, w4, w5, w6, w7;
#define PISS(S, J) { uint2 e_ = sl[8 * (J)]; v##S = __uint_as_float(e_.y); \
    w##S = *(const float3*)(cb + e_.x); }
#define PCON(S, JN, MORE) { float3 W_ = w##S; float V_ = v##S; \
    if (MORE) PISS(S, (JN)) \
    a0 += V_ * W_.x; a1 += V_ * W_.y; a2 += V_ * W_.z; }
    PISS(0,0) PISS(1,1) PISS(2,2) PISS(3,3)
    PISS(4,4) PISS(5,5) PISS(6,6) PISS(7,7)
    #pragma unroll 1
    for (int j = 0; j < m; j += 8) {
        const int jn = j + 8;
        const bool more = jn < m;
        PCON(0,jn+0,more) PCON(1,jn+1,more) PCON(2,jn+2,more) PCON(3,jn+3,more)
        PCON(4,jn+4,more) PCON(5,jn+5,more) PCON(6,jn+6,more) PCON(7,jn+7,more)
    }
#undef PISS
#undef PCON
}

// ---- main kernel: 256 WGs = 64 batches x 4 unit-quarters (both layers) ----
// r16 structure; sync rebuilt WITHOUT release semantics:
//  * entry publishes = agent RELAXED atomic stores (write-through to LLC,
//    no dirty L2 allocation, no flush);
//  * S4 __syncthreads drains vmcnt(0) per wave -> entry stores are complete
//    at the LLC before the count word is even issued;
//  * count word = agent RELAXED atomic store (tag8|cC|cB|cA).
// 4-deep rotation + mod-256 tag: skew bound 3 < 4 -> race-free (r16 proof,
// with completion-before-flag now enforced by the vmcnt drain).
__global__ __launch_bounds__(1024, 4)
void dgru_q(const float* __restrict__ x,
            const float* __restrict__ wih0p,   // [6][512] float3
            const float* __restrict__ whh0p,   // [512][512] float3
            const float* __restrict__ wih1p,
            const float* __restrict__ whh1p,
            const float* __restrict__ bih0, const float* __restrict__ bhh0,
            const float* __restrict__ bih1, const float* __restrict__ bhh1,
            const float* __restrict__ wfc,
            uint2* __restrict__ lists, int* __restrict__ cnts,
            float* __restrict__ ws_fc) {
    __shared__ float s_x[2 * NT];                  // 8 KB
    __shared__ float s_dx0[8];
    __shared__ float s_xp0[8];
    __shared__ unsigned s_cw[4];
    __shared__ uint2 s_lA[576], s_lB[576], s_lC[576];   // 13.5 KB
    __shared__ float s_pp[8][12][128];             // 48 KB slot partials
    __shared__ int   s_c1[2], s_c2[2], s_c3[2];
    __shared__ float s_fcp[2][2];

    const int wgid = blockIdx.x;
    const int bq   = wgid >> 2;
    const int q    = wgid & 3;
    const int tid  = threadIdx.x;
    const int lane = tid & 63;
    const int wave = tid >> 6;        // 0..15
    const int slot = tid >> 7;        // 0..7, wave-uniform
    const int u    = tid & 127;
    const int uu   = q * 128 + u;     // global unit id

    // carries + unit state for BOTH layers (tid<128 meaningful)
    float cr0 = 0.f, cz0 = 0.f, cn0 = 0.f, cnh0 = 0.f;
    float cr1 = 0.f, cz1 = 0.f, cn1 = 0.f, cnh1 = 0.f;
    float h0 = 0.f, h0p = 0.f, xp1 = 0.f, h1 = 0.f, h1p = 0.f;
    float wfc0 = 0.f, wfc1 = 0.f;
    if (tid < 128) {
        cr0  = bih0[uu]         + bhh0[uu];
        cz0  = bih0[HID + uu]   + bhh0[HID + uu];
        cn0  = bih0[2*HID + uu];
        cnh0 = bhh0[2*HID + uu];
        cr1  = bih1[uu]         + bhh1[uu];
        cz1  = bih1[HID + uu]   + bhh1[HID + uu];
        cn1  = bih1[2*HID + uu];
        cnh1 = bhh1[2*HID + uu];
        wfc0 = wfc[uu]; wfc1 = wfc[HID + uu];
    }

    // per-thread column bases (12 B per unit)
    const char* c_ih0 = (const char*)wih0p + uu * 12;
    const char* c_hh0 = (const char*)whh0p + uu * 12;
    const char* c_ih1 = (const char*)wih1p + uu * 12;
    const char* c_hh1 = (const char*)whh1p + uu * 12;

    for (int i = tid; i < 2 * NT; i += 1024) s_x[i] = x[bq * 2 * NT + i];
    if (tid < 8) { s_xp0[tid] = 0.f; s_dx0[tid] = 0.f; }
    __syncthreads();

    for (int t = 0; t <= NT; ++t) {
        const int slot_r = (t + 3) & 3;    // (t-1) mod 4: data published at t-1
        const int slot_w = t & 3;
        // ===== S0: poll the 4 quarter count-words (4 lanes), broadcast =====
        if (tid < 4) {
            const unsigned expct = (unsigned)(t & 0xFF);
            const int* wp = &cnts[widx(slot_r, bq, tid)];
            unsigned v;
            while (((v = (unsigned)ld_cnt(wp)) >> 24) != expct)
                __builtin_amdgcn_s_sleep(2);
            s_cw[tid] = v;
        }
        __syncthreads();                                     // S0
        int cA[4], cB[4], cC[4];
        int nA = 0, nB = 0, nC = 0;
        #pragma unroll
        for (int qq = 0; qq < 4; ++qq) {
            unsigned v = s_cw[qq];
            cA[qq] = (int)(v & 0xFF);
            cB[qq] = (int)((v >> 8) & 0xFF);
            cC[qq] = (int)((v >> 16) & 0xFF);
            nA += cA[qq]; nB += cB[qq]; nC += cC[qq];
        }
        const int nAp = (nA + 63) & ~63;
        const int nBp = (nB + 63) & ~63;
        const int nCp = (nC + 63) & ~63;

        // ===== stage phase: needed lists -> LDS (merged, k ascending) =====
        if (t < NT) {
            for (int i = tid; i < nAp; i += 1024) {
                if (i < nA) {
                    int xx = i, qq = 0;
                    while (xx >= cA[qq]) { xx -= cA[qq]; ++qq; }
                    s_lA[i] = ld_ent(lists + lofs(0, slot_r, bq, qq) + xx);
                } else s_lA[i] = make_uint2(0u, 0u);
            }
            if (tid < 6) {                        // input features, step t
                float iv = s_x[2 * t], qv = s_x[2 * t + 1];
                float amp = sqrtf(iv * iv + qv * qv);
                float f;
                if      (tid == 0) f = iv;
                else if (tid == 1) f = qv;
                else if (tid == 2) f = amp;
                else if (tid == 3) f = amp * amp * amp;
                else if (tid == 4) f = qv / amp;
                else               f = iv / amp;
                float dx = f - s_xp0[tid];
                if (fabsf(dx) < THX) dx = 0.f; else s_xp0[tid] = f;
                s_dx0[tid] = dx;
            }
        }
        if (t > 0) {
            for (int i = tid; i < nBp; i += 1024) {
                if (i < nB) {
                    int xx = i, qq = 0;
                    while (xx >= cB[qq]) { xx -= cB[qq]; ++qq; }
                    s_lB[i] = ld_ent(lists + lofs(1, slot_r, bq, qq) + xx);
                } else s_lB[i] = make_uint2(0u, 0u);
            }
            for (int i = tid; i < nCp; i += 1024) {
                if (i < nC) {
                    int xx = i, qq = 0;
                    while (xx >= cC[qq]) { xx -= cC[qq]; ++qq; }
                    s_lC[i] = ld_ent(lists + lofs(2, slot_r, bq, qq) + xx);
                } else s_lC[i] = make_uint2(0u, 0u);
            }
        }
        __syncthreads();                                     // S1

        // ===== MAC phase: slot-parallel over both layers ==================
        if (t < NT) {
            float hR = 0.f, hZ = 0.f, hNH = 0.f;
            mac3s(s_lA + slot, nAp >> 3, c_hh0, hR, hZ, hNH);
            s_pp[slot][0][u] = hR;
            s_pp[slot][1][u] = hZ;
            s_pp[slot][2][u] = hNH;
            if (slot == 0) {                      // dense ih0 (6 features)
                float iR = 0.f, iZ = 0.f, iN = 0.f;
                #pragma unroll
                for (int f = 0; f < 6; ++f) {     // dv==0 adds exact +0
                    float dv = s_dx0[f];
                    float3 w = *(const float3*)(c_ih0 + f * 6144);
                    iR += dv * w.x; iZ += dv * w.y; iN += dv * w.z;
                }
                s_pp[0][3][u] = iR;
                s_pp[0][4][u] = iZ;
                s_pp[0][5][u] = iN;
            }
        }
        if (t > 0) {
            float iR = 0.f, iZ = 0.f, iN = 0.f;
            float hR = 0.f, hZ = 0.f, hNH = 0.f;
            mac3s(s_lB + slot, nBp >> 3, c_ih1, iR, iZ, iN);
            mac3s(s_lC + slot, nCp >> 3, c_hh1, hR, hZ, hNH);
            s_pp[slot][6][u]  = iR;
            s_pp[slot][7][u]  = iZ;
            s_pp[slot][8][u]  = iN;
            s_pp[slot][9][u]  = hR;
            s_pp[slot][10][u] = hZ;
            s_pp[slot][11][u] = hNH;
        }
        __syncthreads();                                     // S2

        // ===== unit phase (tid<128): merge, gates, deltas, FC =============
        float dA = 0.f, dB = 0.f, dC = 0.f;
        bool nzA = false, nzB = false, nzC = false;
        unsigned long long mA = 0, mB = 0, mC = 0;
        if (tid < 128) {
            if (t < NT) {
                float mhR = 0.f, mhZ = 0.f, mhN = 0.f;
                #pragma unroll
                for (int s = 0; s < 8; ++s) {
                    mhR += s_pp[s][0][u]; mhZ += s_pp[s][1][u]; mhN += s_pp[s][2][u];
                }
                float ar  = cr0 + s_pp[0][3][u] + mhR;   // carry + mac_x + mac_h
                float az  = cz0 + s_pp[0][4][u] + mhZ;
                float an  = cn0 + s_pp[0][5][u];
                float anh = cnh0 + mhN;
                cr0 = ar; cz0 = az; cn0 = an; cnh0 = anh;
                float r = 1.f / (1.f + expf(-ar));
                float z = 1.f / (1.f + expf(-az));
                float n = tanhf(an + r * anh);
                h0 = (1.f - z) * n + z * h0;
                dA = h0 - h0p; if (fabsf(dA) < THH) dA = 0.f; else h0p = h0;
                dB = h0 - xp1; if (fabsf(dB) < THX) dB = 0.f; else xp1 = h0;
                nzA = dA != 0.f; nzB = dB != 0.f;
            }
            if (t > 0) {
                float xiR = 0.f, xiZ = 0.f, xiN = 0.f;
                float mhR = 0.f, mhZ = 0.f, mhN = 0.f;
                #pragma unroll
                for (int s = 0; s < 8; ++s) {
                    xiR += s_pp[s][6][u];  xiZ += s_pp[s][7][u];  xiN += s_pp[s][8][u];
                    mhR += s_pp[s][9][u];  mhZ += s_pp[s][10][u]; mhN += s_pp[s][11][u];
                }
                float ar  = cr1 + xiR + mhR;
                float az  = cz1 + xiZ + mhZ;
                float an  = cn1 + xiN;
                float anh = cnh1 + mhN;
                cr1 = ar; cz1 = az; cn1 = an; cnh1 = anh;
                float r = 1.f / (1.f + expf(-ar));
                float z = 1.f / (1.f + expf(-az));
                float n = tanhf(an + r * anh);
                h1 = (1.f - z) * n + z * h1;
                float p0 = h1 * wfc0, p1 = h1 * wfc1;
                #pragma unroll
                for (int off = 32; off > 0; off >>= 1) {
                    p0 += __shfl_down(p0, off, 64);
                    p1 += __shfl_down(p1, off, 64);
                }
                if (lane == 0) { s_fcp[wave][0] = p0; s_fcp[wave][1] = p1; }
                if (t < NT) {
                    dC = h1 - h1p; if (fabsf(dC) < THH) dC = 0.f; else h1p = h1;
                    nzC = dC != 0.f;
                }
            }
            mA = __ballot(nzA); mB = __ballot(nzB); mC = __ballot(nzC);
            if (lane == 0) {
                s_c1[wave] = __popcll(mA);
                s_c2[wave] = __popcll(mB);
                s_c3[wave] = __popcll(mC);
            }
        }
        __syncthreads();                                     // S3

        // ===== publish phase: entries via RELAXED LLC stores ==============
        if (tid < 128 && t < NT) {
            unsigned long long below = (1ull << lane) - 1;
            int preA = (wave == 1) ? s_c1[0] : 0;
            int preB = (wave == 1) ? s_c2[0] : 0;
            int preC = (wave == 1) ? s_c3[0] : 0;
            uint2* outA = lists + lofs(0, slot_w, bq, q);
            uint2* outB = lists + lofs(1, slot_w, bq, q);
            uint2* outC = lists + lofs(2, slot_w, bq, q);
            if (nzA) st_ent(&outA[preA + __popcll(mA & below)],
                            (unsigned)(uu * 6144u), __float_as_uint(dA));
            if (nzB) st_ent(&outB[preB + __popcll(mB & below)],
                            (unsigned)(uu * 6144u), __float_as_uint(dB));
            if (nzC) st_ent(&outC[preC + __popcll(mC & below)],
                            (unsigned)(uu * 6144u), __float_as_uint(dC));
        }
        if (t > 0 && tid == 0) {
            float2* dst = (float2*)(ws_fc + (((size_t)bq * NT + (t - 1)) * 4 + q) * 2);
            *dst = make_float2(s_fcp[0][0] + s_fcp[1][0],
                               s_fcp[0][1] + s_fcp[1][1]);
        }
        __syncthreads();     // S4: vmcnt(0) drain -> entry stores complete at LLC

        // ===== publish packed count word (RELAXED: ordering by S4 drain) ==
        if (t < NT && tid == 0) {
            unsigned word = ((unsigned)((t + 1) & 0xFF) << 24)
                          | ((unsigned)(s_c3[0] + s_c3[1]) << 16)
                          | ((unsigned)(s_c2[0] + s_c2[1]) << 8)
                          |  (unsigned)(s_c1[0] + s_c1[1]);
            st_cnt(&cnts[widx(slot_w, bq, q)], (int)word);
        }
    }
}

// ---- epilogue: deterministic FC reduction over 4 quarters (ascending) ----
__global__ void fc_reduce(const float* __restrict__ ws_fc,
                          const float* __restrict__ bfc,
                          float* __restrict__ out) {
    int idx = blockIdx.x * blockDim.x + threadIdx.x;   // (b*NT + t)
    if (idx < NB * NT) {
        const float2* p = (const float2*)(ws_fc + (size_t)idx * 8);
        out[idx * 2 + 0] = bfc[0] + p[0].x + p[1].x + p[2].x + p[3].x;
        out[idx * 2 + 1] = bfc[1] + p[0].y + p[1].y + p[2].y + p[3].y;
    }
}

// ---- safety-net fallback (ws too small): dense branchy loops, inline FC ----
__global__ __launch_bounds__(512)
void dgru_raw(const float* __restrict__ x,
              const float* __restrict__ wih0, const float* __restrict__ whh0,
              const float* __restrict__ wih1, const float* __restrict__ whh1,
              const float* __restrict__ bih0, const float* __restrict__ bhh0,
              const float* __restrict__ bih1, const float* __restrict__ bhh1,
              const float* __restrict__ wfc,  const float* __restrict__ bfc,
              float* __restrict__ out) {
    __shared__ float s_dx0[8];
    __shared__ float s_xp0[8];
    __shared__ float s_dh0[HID];
    __shared__ float s_dx1[HID];
    __shared__ float s_dh1[HID];
    __shared__ float s_part[16];

    const int j = threadIdx.x;
    const int b = blockIdx.x;
    float h0 = 0.f, h0p = 0.f, xp1 = 0.f, h1 = 0.f, h1p = 0.f;
    float cr0 = bih0[j] + bhh0[j];
    float cz0 = bih0[HID + j] + bhh0[HID + j];
    float cn0 = bih0[2*HID + j];
    float cnh0 = bhh0[2*HID + j];
    float cr1 = bih1[j] + bhh1[j];
    float cz1 = bih1[HID + j] + bhh1[HID + j];
    float cn1 = bih1[2*HID + j];
    float cnh1 = bhh1[2*HID + j];
    if (j < 8) { s_xp0[j] = 0.f; s_dx0[j] = 0.f; }
    const float wfc0 = wfc[j], wfc1 = wfc[HID + j];
    __syncthreads();

    for (int t = 0; t < NT; ++t) {
        float d = h0 - h0p;
        if (fabsf(d) < THH) d = 0.f; else h0p = h0;
        s_dh0[j] = d;
        if (j < 6) {
            float iv = x[(b * NT + t) * 2 + 0];
            float qv = x[(b * NT + t) * 2 + 1];
            float amp = sqrtf(iv * iv + qv * qv);
            float f;
            if      (j == 0) f = iv;
            else if (j == 1) f = qv;
            else if (j == 2) f = amp;
            else if (j == 3) f = amp * amp * amp;
            else if (j == 4) f = qv / amp;
            else             f = iv / amp;
            float dx = f - s_xp0[j];
            if (fabsf(dx) < THX) dx = 0.f; else s_xp0[j] = f;
            s_dx0[j] = dx;
        }
        __syncthreads();
        {
            float ar = cr0, az = cz0, an = cn0, anh = cnh0;
            #pragma unroll
            for (int f = 0; f < 6; ++f) {
                float dv = s_dx0[f];
                ar += dv * wih0[j * 6 + f];
                az += dv * wih0[(HID + j) * 6 + f];
                an += dv * wih0[(2*HID + j) * 6 + f];
            }
            for (int k = 0; k < HID; ++k) {
                float dv = s_dh0[k];
                if (dv != 0.f) {
                    ar  += dv * whh0[j * HID + k];
                    az  += dv * whh0[(HID + j) * HID + k];
                    anh += dv * whh0[(2*HID + j) * HID + k];
                }
            }
            cr0 = ar; cz0 = az; cn0 = an; cnh0 = anh;
            float r = 1.f / (1.f + expf(-ar));
            float z = 1.f / (1.f + expf(-az));
            float n = tanhf(an + r * anh);
            h0 = (1.f - z) * n + z * h0;
        }
        float dxv = h0 - xp1;
        if (fabsf(dxv) < THX) dxv = 0.f; else xp1 = h0;
        s_dx1[j] = dxv;
        float dhv = h1 - h1p;
        if (fabsf(dhv) < THH) dhv = 0.f; else h1p = h1;
        s_dh1[j] = dhv;
        __syncthreads();
        {
            float ar = cr1, az = cz1, an = cn1, anh = cnh1;
            for (int k = 0; k < HID; ++k) {
                float dv = s_dx1[k];
                if (dv != 0.f) {
                    ar += dv * wih1[j * HID + k];
                    az += dv * wih1[(HID + j) * HID + k];
                    an += dv * wih1[(2*HID + j) * HID + k];
                }
            }
            for (int k = 0; k < HID; ++k) {
                float dv = s_dh1[k];
                if (dv != 0.f) {
                    ar  += dv * whh1[j * HID + k];
                    az  += dv * whh1[(HID + j) * HID + k];
                    anh += dv * whh1[(2*HID + j) * HID + k];
                }
            }
            cr1 = ar; cz1 = az; cn1 = an; cnh1 = anh;
            float r = 1.f / (1.f + expf(-ar));
            float z = 1.f / (1.f + expf(-az));
            float n = tanhf(an + r * anh);
            h1 = (1.f - z) * n + z * h1;
        }
        float p0 = h1 * wfc0, p1 = h1 * wfc1;
        #pragma unroll
        for (int off = 32; off > 0; off >>= 1) {
            p0 += __shfl_down(p0, off, 64);
            p1 += __shfl_down(p1, off, 64);
        }
        if ((j & 63) == 0) { s_part[(j >> 6) * 2] = p0; s_part[(j >> 6) * 2 + 1] = p1; }
        __syncthreads();
        if (j == 0) {
            float o0 = bfc[0], o1 = bfc[1];
            #pragma unroll
            for (int w = 0; w < 8; ++w) { o0 += s_part[w * 2]; o1 += s_part[w * 2 + 1]; }
            out[(b * NT + t) * 2 + 0] = o0;
            out[(b * NT + t) * 2 + 1] = o1;
        }
    }
}

extern "C" void kernel_launch(void* const* d_in, const int* in_sizes, int n_in,
                              void* d_out, int out_size, void* d_ws, size_t ws_size,
                              hipStream_t stream) {
    const float* x    = (const float*)d_in[0];
    // d_in[1] = h_0 : reference zero-inits h, input unused
    const float* wih0 = (const float*)d_in[2];
    const float* whh0 = (const float*)d_in[3];
    const float* bih0 = (const float*)d_in[4];
    const float* bhh0 = (const float*)d_in[5];
    const float* wih1 = (const float*)d_in[6];
    const float* whh1 = (const float*)d_in[7];
    const float* bih1 = (const float*)d_in[8];
    const float* bhh1 = (const float*)d_in[9];
    const float* wfc  = (const float*)d_in[10];
    const float* bfc  = (const float*)d_in[11];
    float* out = (float*)d_out;

    const size_t MAT3    = (size_t)HID * 1536 * sizeof(float);     // 3 MiB each
    const size_t o_ih0   = 0;                                       // 36,864 B
    const size_t o_hh0   = 6 * 1536 * sizeof(float);
    const size_t o_ih1   = o_hh0 + MAT3;
    const size_t o_hh1   = o_ih1 + MAT3;
    const size_t o_lists = o_hh1 + MAT3;
    const size_t LISTS_B = (size_t)3 * 4 * NB * 4 * 128 * 8;        // 3 MiB (4-deep)
    const size_t o_cnts  = o_lists + LISTS_B;
    const size_t o_fc    = o_cnts + (size_t)4 * NB * 4 * sizeof(int);
    const size_t FCB     = (size_t)NB * NT * 4 * 2 * sizeof(float); // 2 MiB
    const size_t need    = o_fc + FCB;                              // ~14.2 MiB

    if (ws_size >= need) {
        float* wt_ih0 = (float*)((char*)d_ws + o_ih0);
        float* wt_hh0 = (float*)((char*)d_ws + o_hh0);
        float* wt_ih1 = (float*)((char*)d_ws + o_ih1);
        float* wt_hh1 = (float*)((char*)d_ws + o_hh1);
        uint2* g_lists = (uint2*)((char*)d_ws + o_lists);
        int*   g_cnts  = (int*)((char*)d_ws + o_cnts);
        float* g_fc    = (float*)((char*)d_ws + o_fc);

        pack_ih0<<<(6 * HID + 255) / 256, 256, 0, stream>>>(wih0, wt_ih0);
        pack_h3<<<(HID * HID + 255) / 256, 256, 0, stream>>>(whh0, wt_hh0);
        pack_h3<<<(HID * HID + 255) / 256, 256, 0, stream>>>(wih1, wt_ih1);
        pack_h3<<<(HID * HID + 255) / 256, 256, 0, stream>>>(whh1, wt_hh1);
        init_ws<<<1, 1024, 0, stream>>>(g_cnts);
        dgru_q<<<4 * NB, 1024, 0, stream>>>(x, wt_ih0, wt_hh0, wt_ih1, wt_hh1,
                                            bih0, bhh0, bih1, bhh1, wfc,
                                            g_lists, g_cnts, g_fc);
        fc_reduce<<<(NB * NT + 255) / 256, 256, 0, stream>>>(g_fc, bfc, out);
    } else {
        dgru_raw<<<NB, HID, 0, stream>>>(x, wih0, whh0, wih1, whh1,
                                         bih0, bhh0, bih1, bhh1, wfc, bfc, out);
    }
}